// Round 7
// baseline (327.570 us; speedup 1.0000x reference)
//
#include <hip/hip_runtime.h>
#include <hip/hip_bf16.h>
#include <stdint.h>

// Problem constants (B,T,E,H,HD,FF) = (2,2048,1024,16,64,4096).
// I/O dtype: float32. Internal GEMM/attention compute: bf16 MFMA, fp32 accumulate.
#define T_SEQ 2048
#define E_DIM 1024
#define H_NUM 16
#define HD_DIM 64
#define FF_DIM 4096
#define B_NUM 2
#define N_TOK (B_NUM * T_SEQ) // 4096 token rows

typedef unsigned short ushort_t;
typedef __bf16 bf16x8 __attribute__((ext_vector_type(8)));
typedef float f32x4 __attribute__((ext_vector_type(4)));

__device__ __forceinline__ float bf2f(ushort_t u) {
    return __uint_as_float(((unsigned)u) << 16);
}
__device__ __forceinline__ ushort_t f2bf(float f) {
    unsigned u = __float_as_uint(f);
    u += 0x7fffu + ((u >> 16) & 1u);   // round-to-nearest-even
    return (ushort_t)(u >> 16);
}
__device__ __forceinline__ float bflo(unsigned u) { return __uint_as_float(u << 16); }
__device__ __forceinline__ float bfhi(unsigned u) { return __uint_as_float(u & 0xffff0000u); }

// Async global->LDS, 16B per lane. LDS dst is wave-uniform base + lane*16 in
// issue order -> LDS image layout is contiguous in ci order.
__device__ __forceinline__ void async_copy16(const ushort_t* g, ushort_t* l) {
    __builtin_amdgcn_global_load_lds(
        (__attribute__((address_space(1))) uint32_t*)(ushort_t*)g,
        (__attribute__((address_space(3))) uint32_t*)l, 16, 0, 0);
}

// ---------------- LayerNorm: one block per row of 1024; fp32 in, bf16 out ----
__global__ __launch_bounds__(256) void ln_kernel(const float* __restrict__ x,
                                                 const float* __restrict__ g,
                                                 const float* __restrict__ be,
                                                 ushort_t* __restrict__ out) {
    __shared__ float red[8];
    const int row = blockIdx.x, tid = threadIdx.x;
    const float* xr = x + (size_t)row * E_DIM;
    float4 v = ((const float4*)xr)[tid];   // 4 fp32 per thread
    float s = v.x + v.y + v.z + v.w;
    float sq = v.x * v.x + v.y * v.y + v.z * v.z + v.w * v.w;
    for (int off = 32; off; off >>= 1) {
        s += __shfl_xor(s, off);
        sq += __shfl_xor(sq, off);
    }
    const int wid = tid >> 6, lane = tid & 63;
    if (lane == 0) { red[wid] = s; red[4 + wid] = sq; }
    __syncthreads();
    s = red[0] + red[1] + red[2] + red[3];
    sq = red[4] + red[5] + red[6] + red[7];
    const float mean = s * (1.0f / E_DIM);
    const float var = sq * (1.0f / E_DIM) - mean * mean;
    const float rstd = rsqrtf(var + 1e-5f);
    float4 gv = ((const float4*)g)[tid];
    float4 bv = ((const float4*)be)[tid];
    unsigned o0 = f2bf((v.x - mean) * rstd * gv.x + bv.x);
    unsigned o1 = f2bf((v.y - mean) * rstd * gv.y + bv.y);
    unsigned o2 = f2bf((v.z - mean) * rstd * gv.z + bv.z);
    unsigned o3 = f2bf((v.w - mean) * rstd * gv.w + bv.w);
    uint2 w;
    w.x = o0 | (o1 << 16);
    w.y = o2 | (o3 << 16);
    ((uint2*)(out + (size_t)row * E_DIM))[tid] = w;
}

// ---- proj split-K reduce + residual + LN2 fused: one block per token row ----
// v = x + bproj + p0 + p1 ; x1 = v (fp32) ; h2 = LN(v)*g2+be2 (bf16)
__global__ __launch_bounds__(256) void reduce_ln_kernel(const ushort_t* __restrict__ p0,
                                                        const ushort_t* __restrict__ p1,
                                                        const float* __restrict__ x,
                                                        const float* __restrict__ bias,
                                                        const float* __restrict__ g,
                                                        const float* __restrict__ be,
                                                        float* __restrict__ x1,
                                                        ushort_t* __restrict__ h2) {
    __shared__ float red[8];
    const int row = blockIdx.x, tid = threadIdx.x;
    uint2 u0 = ((const uint2*)(p0 + (size_t)row * E_DIM))[tid];
    uint2 u1 = ((const uint2*)(p1 + (size_t)row * E_DIM))[tid];
    float4 xv = ((const float4*)(x + (size_t)row * E_DIM))[tid];
    float4 bv = ((const float4*)bias)[tid];
    float4 v;
    v.x = xv.x + bv.x + bflo(u0.x) + bflo(u1.x);
    v.y = xv.y + bv.y + bfhi(u0.x) + bfhi(u1.x);
    v.z = xv.z + bv.z + bflo(u0.y) + bflo(u1.y);
    v.w = xv.w + bv.w + bfhi(u0.y) + bfhi(u1.y);
    ((float4*)(x1 + (size_t)row * E_DIM))[tid] = v;
    float s = v.x + v.y + v.z + v.w;
    float sq = v.x * v.x + v.y * v.y + v.z * v.z + v.w * v.w;
    for (int off = 32; off; off >>= 1) {
        s += __shfl_xor(s, off);
        sq += __shfl_xor(sq, off);
    }
    const int wid = tid >> 6, lane = tid & 63;
    if (lane == 0) { red[wid] = s; red[4 + wid] = sq; }
    __syncthreads();
    s = red[0] + red[1] + red[2] + red[3];
    sq = red[4] + red[5] + red[6] + red[7];
    const float mean = s * (1.0f / E_DIM);
    const float var = sq * (1.0f / E_DIM) - mean * mean;
    const float rstd = rsqrtf(var + 1e-5f);
    float4 gv = ((const float4*)g)[tid];
    float4 ev = ((const float4*)be)[tid];
    unsigned o0 = f2bf((v.x - mean) * rstd * gv.x + ev.x);
    unsigned o1 = f2bf((v.y - mean) * rstd * gv.y + ev.y);
    unsigned o2 = f2bf((v.z - mean) * rstd * gv.z + ev.z);
    unsigned o3 = f2bf((v.w - mean) * rstd * gv.w + ev.w);
    uint2 w;
    w.x = o0 | (o1 << 16);
    w.y = o2 | (o3 << 16);
    ((uint2*)(h2 + (size_t)row * E_DIM))[tid] = w;
}

// ---- FFN2 split-K reduce + bias + residual: d_out = x1 + b2 + p0 + p1 ------
__global__ __launch_bounds__(256) void reduce_out_kernel(const ushort_t* __restrict__ p0,
                                                         const ushort_t* __restrict__ p1,
                                                         const float* __restrict__ x1,
                                                         const float* __restrict__ bias,
                                                         float* __restrict__ out) {
    const int row = blockIdx.x, tid = threadIdx.x;
    uint2 u0 = ((const uint2*)(p0 + (size_t)row * E_DIM))[tid];
    uint2 u1 = ((const uint2*)(p1 + (size_t)row * E_DIM))[tid];
    float4 xv = ((const float4*)(x1 + (size_t)row * E_DIM))[tid];
    float4 bv = ((const float4*)bias)[tid];
    float4 v;
    v.x = xv.x + bv.x + bflo(u0.x) + bflo(u1.x);
    v.y = xv.y + bv.y + bfhi(u0.x) + bfhi(u1.x);
    v.z = xv.z + bv.z + bflo(u0.y) + bflo(u1.y);
    v.w = xv.w + bv.w + bfhi(u0.y) + bfhi(u1.y);
    ((float4*)(out + (size_t)row * E_DIM))[tid] = v;
}

// -------- Merged convert-transposes (fp32 weights -> bf16 B^T layouts) -------
//   [0,3072)      Wq/Wk/Wv [H][1024][64] -> WqkvT rows (mat*1024+h*64+d) over E
//   [3072,4096)   Wproj 1024x1024 -> WprojT
//   [4096,8192)   W1 1024x4096 -> W1T
//   [8192,12288)  W2 4096x1024 -> W2T
__global__ __launch_bounds__(256) void transpose_all_kernel(const float* __restrict__ Wq,
                                                            const float* __restrict__ Wk,
                                                            const float* __restrict__ Wv,
                                                            const float* __restrict__ Wproj,
                                                            const float* __restrict__ W1,
                                                            const float* __restrict__ W2,
                                                            ushort_t* __restrict__ WqkvT,
                                                            ushort_t* __restrict__ WprojT,
                                                            ushort_t* __restrict__ W1T,
                                                            ushort_t* __restrict__ W2T) {
    __shared__ ushort_t tile[32][33];
    const int id = blockIdx.x;
    const float* in;
    ushort_t* out;
    int R, C, r0, c0;
    if (id < 3072) {
        const int z = id >> 6, rem = id & 63;   // z: 3 mats x 16 heads
        const int m = z >> 4, hh = z & 15;
        in = ((m == 0) ? Wq : ((m == 1) ? Wk : Wv)) + (size_t)hh * E_DIM * HD_DIM; // [1024][64]
        out = WqkvT + (size_t)(m * E_DIM + hh * HD_DIM) * E_DIM;
        R = E_DIM; C = HD_DIM;
        c0 = (rem & 1) * 32; r0 = (rem >> 1) * 32;
    } else if (id < 4096) {
        const int i = id - 3072;
        in = Wproj; out = WprojT; R = E_DIM; C = E_DIM;
        c0 = (i & 31) * 32; r0 = (i >> 5) * 32;
    } else if (id < 8192) {
        const int i = id - 4096;
        in = W1; out = W1T; R = E_DIM; C = FF_DIM;
        c0 = (i & 127) * 32; r0 = (i >> 7) * 32;
    } else {
        const int i = id - 8192;
        in = W2; out = W2T; R = FF_DIM; C = E_DIM;
        c0 = (i & 31) * 32; r0 = (i >> 5) * 32;
    }
    const int tx = threadIdx.x, ty = threadIdx.y;
#pragma unroll
    for (int i = 0; i < 32; i += 8) tile[ty + i][tx] = f2bf(in[(size_t)(r0 + ty + i) * C + (c0 + tx)]);
    __syncthreads();
#pragma unroll
    for (int i = 0; i < 32; i += 8) out[(size_t)(c0 + ty + i) * R + (r0 + tx)] = tile[tx][ty + i];
}

// ---------------- 256x256 8-phase GEMM (T2+T3+T4+T5), FFN1 ------------------
// Grid (N/256, M/256), 512 thr, 8 waves 2Mx4N; per-wave C = 128x64 (8x4
// frags). BK=64, double-buffered 128 KiB LDS, half-tile (128 rows x 64 k)
// staging granularity. Schedule per K-tile kt (4 phases; phase p computes
// m-pair {2p,2p+1} x K=64):
//   phase: { ds-read A-frags (+all 8 B-frags at p0); stage ONE half-tile;
//            s_barrier; lgkmcnt(0); setprio(1); 16 MFMA; setprio(0);
//            [p3: counted vmcnt(4)]; s_barrier }
// Stage targets: p0/p1: A-halves(kt+1)->buf^1; p2/p3: B-halves(kt+2)->buf.
// vmcnt(4) at p3 keeps B(kt+2)'s 4 loads in flight across the tile boundary;
// A(kt+1)+B(kt+1) guaranteed landed for kt+1 p0.
// LDS XOR swizzle (T2): 16B chunk' = chunk ^ (row&7) on global src + ds_read
// addr (rule #21). r1 measured: BANK_CONFLICT 4.19M->0. Epilogue fm-outer
// (r2 verified: no partial-line L2 writeback amplification).
__global__ __launch_bounds__(512, 2) void gemm256_ffn1(const ushort_t* __restrict__ A,
                                                       const ushort_t* __restrict__ BT,
                                                       const float* __restrict__ bias,
                                                       ushort_t* __restrict__ C,
                                                       int N, int K, int lda) {
    __shared__ __align__(16) ushort_t lds_a[2][16384]; // [buf][half:2][128 rows][64 k]
    __shared__ __align__(16) ushort_t lds_b[2][16384];
    const int tid = threadIdx.x;
    // XCD-band swizzle (gridDim.y % 8 == 0; bijective since gy%8==0)
    const int id = blockIdx.y * gridDim.x + blockIdx.x;
    const int band = id & 7, within = id >> 3;
    const int rpb = gridDim.y >> 3;
    const int by = band * rpb + (within % rpb);
    const int bx = within / rpb;
    const int m0 = by * 256, n0 = bx * 256;
    const int wave = tid >> 6, lane = tid & 63;
    const int wr = wave >> 2, wc = wave & 3; // 2M x 4N wave grid
    const int quad = lane >> 4, l16 = lane & 15;
    const int nkt = K >> 6;

    f32x4 acc[8][4] = {};

    auto stageA = [&](int kt, int half) {
        ushort_t* dst = &lds_a[kt & 1][half * 8192];
        const ushort_t* src = A + (size_t)(m0 + half * 128) * lda + kt * 64;
#pragma unroll
        for (int it = 0; it < 2; ++it) {
            const int ci = it * 512 + tid;
            const int r = ci >> 3, c = ci & 7;
            async_copy16(src + (size_t)r * lda + ((c ^ (r & 7)) << 3), dst + ci * 8);
        }
    };
    auto stageB = [&](int kt, int half) {
        ushort_t* dst = &lds_b[kt & 1][half * 8192];
        const ushort_t* src = BT + (size_t)(n0 + half * 128) * lda + kt * 64;
#pragma unroll
        for (int it = 0; it < 2; ++it) {
            const int ci = it * 512 + tid;
            const int r = ci >> 3, c = ci & 7;
            async_copy16(src + (size_t)r * lda + ((c ^ (r & 7)) << 3), dst + ci * 8);
        }
    };

    // Prologue: A(0), B(0), B(1). A(1) comes in kt=0 phases 0-1 (steady state).
    stageA(0, 0); stageA(0, 1);
    stageB(0, 0); stageB(0, 1);
    stageB(1, 0); stageB(1, 1);
    asm volatile("s_waitcnt vmcnt(4)" ::: "memory"); // A(0)+B(0) landed; B(1) in flight
    __builtin_amdgcn_s_barrier();

    const int swz = l16 & 7; // row&7 for all this lane's fragment rows

#pragma unroll 1
    for (int kt = 0; kt < nkt; ++kt) {
        const int buf = kt & 1;
        const ushort_t* la = &lds_a[buf][wr * 8192];           // wave's A half
        const ushort_t* lb = &lds_b[buf][(wc >> 1) * 8192];    // wave's B half
        const int brow = (wc & 1) * 64;
        bf16x8 bfrag[2][4]; // [kk][fn], held across the 4 phases
#pragma unroll
        for (int p = 0; p < 4; ++p) {
            bf16x8 af[2][2]; // [sub-m][kk]
#pragma unroll
            for (int s = 0; s < 2; ++s) {
                const int r = (p * 2 + s) * 16 + l16;
#pragma unroll
                for (int kk = 0; kk < 2; ++kk)
                    af[s][kk] = *(const bf16x8*)&la[r * 64 + (((kk << 2) + quad) ^ swz) * 8];
            }
            if (p == 0) {
#pragma unroll
                for (int kk = 0; kk < 2; ++kk)
#pragma unroll
                    for (int fn = 0; fn < 4; ++fn) {
                        const int r = brow + fn * 16 + l16;
                        bfrag[kk][fn] = *(const bf16x8*)&lb[r * 64 + (((kk << 2) + quad) ^ swz) * 8];
                    }
            }
            if (p == 0) { if (kt + 1 < nkt) stageA(kt + 1, 0); }
            else if (p == 1) { if (kt + 1 < nkt) stageA(kt + 1, 1); }
            else if (p == 2) { if (kt + 2 < nkt) stageB(kt + 2, 0); }
            else { if (kt + 2 < nkt) stageB(kt + 2, 1); }

            __builtin_amdgcn_s_barrier();
            asm volatile("s_waitcnt lgkmcnt(0)" ::: "memory");
            __builtin_amdgcn_sched_barrier(0);
            __builtin_amdgcn_s_setprio(1);
#pragma unroll
            for (int s = 0; s < 2; ++s)
#pragma unroll
                for (int kk = 0; kk < 2; ++kk)
#pragma unroll
                    for (int fn = 0; fn < 4; ++fn)
                        acc[p * 2 + s][fn] = __builtin_amdgcn_mfma_f32_16x16x32_bf16(
                            af[s][kk], bfrag[kk][fn], acc[p * 2 + s][fn], 0, 0, 0);
            __builtin_amdgcn_s_setprio(0);
            if (p == 3) {
                if (kt + 2 < nkt) asm volatile("s_waitcnt vmcnt(4)" ::: "memory");
                else              asm volatile("s_waitcnt vmcnt(0)" ::: "memory");
            }
            __builtin_amdgcn_s_barrier();
        }
    }

    // ---- epilogue: relu(acc + bias) -> bf16 (fm outer: dense row spans) ----
#pragma unroll
    for (int fm = 0; fm < 8; ++fm) {
        const int row_base = m0 + wr * 128 + fm * 16 + quad * 4;
#pragma unroll
        for (int fn = 0; fn < 4; ++fn) {
            const int col = n0 + wc * 64 + fn * 16 + l16;
            const float bv = bias[col];
#pragma unroll
            for (int r = 0; r < 4; ++r)
                C[(size_t)(row_base + r) * N + col] =
                    f2bf(fmaxf(acc[fm][fn][r] + bv, 0.0f));
        }
    }
}

// ------------- 256x192 8-phase GEMM for QKV (full 256-block fill) -----------
// N=3072 -> BN=192: grid 16x16 = 256 blocks = 1/CU full fill. Per-wave C =
// 128x48 (8x3 frags), 12 MFMA/phase. LDS = A 64KB + B 48KB = 112KB.
// B staged as ONE full 192x64 tile (3 loads/thread) at p2; A halves at p0/p1.
// vmcnt ledger: at p3 outstanding = B(kt+1)[3]+A(kt+1)[4]+B(kt+2)[3] = 10;
// vmcnt(3) leaves exactly B(kt+2) in flight. Prologue: 10 loads, vmcnt(3).
// Scatter epilogue = gemm_bt<0> mapping (verified ideal 24.6MB WRITE), fm-outer.
__global__ __launch_bounds__(512, 2) void gemm192_qkv(const ushort_t* __restrict__ A,
                                                      const ushort_t* __restrict__ BT,
                                                      ushort_t* __restrict__ qP,
                                                      ushort_t* __restrict__ kP,
                                                      ushort_t* __restrict__ vP,
                                                      int K, int lda) {
    __shared__ __align__(16) ushort_t lds_a[2][16384]; // [buf][half:2][128 rows][64 k]
    __shared__ __align__(16) ushort_t lds_b[2][12288]; // [buf][192 rows][64 k]
    const int tid = threadIdx.x;
    const int id = blockIdx.y * gridDim.x + blockIdx.x;
    const int band = id & 7, within = id >> 3;
    const int rpb = gridDim.y >> 3; // 2
    const int by = band * rpb + (within % rpb);
    const int bx = within / rpb;
    const int m0 = by * 256, n0 = bx * 192;
    const int wave = tid >> 6, lane = tid & 63;
    const int wr = wave >> 2, wc = wave & 3; // 2M x 4N wave grid, 48 cols/wave
    const int quad = lane >> 4, l16 = lane & 15;
    const int nkt = K >> 6;

    f32x4 acc[8][3] = {};

    auto stageA = [&](int kt, int half) {
        ushort_t* dst = &lds_a[kt & 1][half * 8192];
        const ushort_t* src = A + (size_t)(m0 + half * 128) * lda + kt * 64;
#pragma unroll
        for (int it = 0; it < 2; ++it) {
            const int ci = it * 512 + tid;
            const int r = ci >> 3, c = ci & 7;
            async_copy16(src + (size_t)r * lda + ((c ^ (r & 7)) << 3), dst + ci * 8);
        }
    };
    auto stageB = [&](int kt) { // full 192x64 tile, 3 loads/thread
        ushort_t* dst = lds_b[kt & 1];
        const ushort_t* src = BT + (size_t)n0 * lda + kt * 64;
#pragma unroll
        for (int it = 0; it < 3; ++it) {
            const int ci = it * 512 + tid;
            const int r = ci >> 3, c = ci & 7;
            async_copy16(src + (size_t)r * lda + ((c ^ (r & 7)) << 3), dst + ci * 8);
        }
    };

    stageA(0, 0); stageA(0, 1);
    stageB(0);
    stageB(1);
    asm volatile("s_waitcnt vmcnt(3)" ::: "memory"); // A(0)+B(0) landed; B(1) in flight
    __builtin_amdgcn_s_barrier();

    const int swz = l16 & 7;

#pragma unroll 1
    for (int kt = 0; kt < nkt; ++kt) {
        const int buf = kt & 1;
        const ushort_t* la = &lds_a[buf][wr * 8192]; // wave's 128-row A half
        const ushort_t* lb = lds_b[buf];
        const int brow = wc * 48;
        bf16x8 bfrag[2][3]; // [kk][fn], held across the 4 phases
#pragma unroll
        for (int p = 0; p < 4; ++p) {
            bf16x8 af[2][2]; // [sub-m][kk]
#pragma unroll
            for (int s = 0; s < 2; ++s) {
                const int r = (p * 2 + s) * 16 + l16;
#pragma unroll
                for (int kk = 0; kk < 2; ++kk)
                    af[s][kk] = *(const bf16x8*)&la[r * 64 + (((kk << 2) + quad) ^ swz) * 8];
            }
            if (p == 0) {
#pragma unroll
                for (int kk = 0; kk < 2; ++kk)
#pragma unroll
                    for (int fn = 0; fn < 3; ++fn) {
                        const int r = brow + fn * 16 + l16;
                        bfrag[kk][fn] = *(const bf16x8*)&lb[r * 64 + (((kk << 2) + quad) ^ swz) * 8];
                    }
            }
            if (p == 0) { if (kt + 1 < nkt) stageA(kt + 1, 0); }
            else if (p == 1) { if (kt + 1 < nkt) stageA(kt + 1, 1); }
            else if (p == 2) { if (kt + 2 < nkt) stageB(kt + 2); }

            __builtin_amdgcn_s_barrier();
            asm volatile("s_waitcnt lgkmcnt(0)" ::: "memory");
            __builtin_amdgcn_sched_barrier(0);
            __builtin_amdgcn_s_setprio(1);
#pragma unroll
            for (int s = 0; s < 2; ++s)
#pragma unroll
                for (int kk = 0; kk < 2; ++kk)
#pragma unroll
                    for (int fn = 0; fn < 3; ++fn)
                        acc[p * 2 + s][fn] = __builtin_amdgcn_mfma_f32_16x16x32_bf16(
                            af[s][kk], bfrag[kk][fn], acc[p * 2 + s][fn], 0, 0, 0);
            __builtin_amdgcn_s_setprio(0);
            if (p == 3) {
                if (kt + 2 < nkt) asm volatile("s_waitcnt vmcnt(3)" ::: "memory");
                else              asm volatile("s_waitcnt vmcnt(0)" ::: "memory");
            }
            __builtin_amdgcn_s_barrier();
        }
    }

    // ---- scatter epilogue (fm outer) ----
#pragma unroll
    for (int fm = 0; fm < 8; ++fm) {
        const int row_base = m0 + wr * 128 + fm * 16 + quad * 4;
#pragma unroll
        for (int fn = 0; fn < 3; ++fn) {
            const int col = n0 + wc * 48 + fn * 16 + l16; // [0,3072)
            const int mat = col >> 10, c = col & 1023, hh = c >> 6, d = c & 63;
#pragma unroll
            for (int r = 0; r < 4; ++r) {
                const int row = row_base + r;
                const int bb = row >> 11, tt = row & 2047;
                const int bh = bb * H_NUM + hh;
                float v = acc[fm][fn][r];
                size_t idx;
                ushort_t* dst;
                if (mat == 0) {        // qP [bh][qt:32][ch:8][row:64][8], pre-scaled
                    idx = ((((size_t)bh * 32 + (tt >> 6)) * 8 + (d >> 3)) * 64 + (tt & 63)) * 8 + (d & 7);
                    dst = qP;
                    v *= 0.0450842048f; // E^-0.5 * log2(e): softmax runs in exp2 domain
                } else if (mat == 1) { // kP [bh][kt:32][ch:8][key:64][8]
                    idx = ((((size_t)bh * 32 + (tt >> 6)) * 8 + (d >> 3)) * 64 + (tt & 63)) * 8 + (d & 7);
                    dst = kP;
                } else {               // vP [bh][kt:32][kh:8][d:64][8]  (V transposed)
                    idx = ((((size_t)bh * 32 + (tt >> 6)) * 8 + ((tt & 63) >> 3)) * 64 + d) * 8 + (tt & 7);
                    dst = vP;
                }
                dst[idx] = f2bf(v);
            }
        }
    }
}

// ------------- 256x128 8-phase split-K GEMM (proj + FFN2) -------------------
// C_partial[M,N=narrow] = A[M, K-slice] * BT^T -> bf16 partial (z selects
// output buffer). Grid (N/128, M/256, nz); full 256-block fill for
// FFN2 (8x16x2) and proj (8x16x2). Per-wave C = 128x32 (8x2 frags),
// 8 MFMA/phase. LDS = A 64KB + B 32KB = 96KB -> 1 block/CU.
// Staging: p0/p1 = A halves(kt+1) (2 loads/thr each); p2 = B(kt+2) full
// 128x64 tile (2 loads/thr); p3 = none.
// vmcnt ledger (steady state at p3): outstanding = B(kt+1)[2] + A(kt+1)[4] +
// B(kt+2)[2] = 8 -> vmcnt(2) leaves exactly B(kt+2) in flight; A(kt+1) and
// B(kt+1) guaranteed landed for kt+1 p0. Prologue: A(0)h0,h1 + B(0) + B(1)
// = 8 loads; vmcnt(2) -> A(0)+B(0) landed, B(1) flying.
// Replaces 2-phase gemm_bt<3,64> (r6 measured: FFN2 48.6us / 707 TF, 32
// vmcnt(0) drains per block -- the 2-phase critical path, m233).
__global__ __launch_bounds__(512, 2) void gemm128n(const ushort_t* __restrict__ A,
                                                   const ushort_t* __restrict__ BT,
                                                   ushort_t* __restrict__ P0,
                                                   ushort_t* __restrict__ P1,
                                                   int N, int K, int lda) {
    __shared__ __align__(16) ushort_t lds_a[2][16384]; // [buf][half:2][128 rows][64 k]
    __shared__ __align__(16) ushort_t lds_b[2][8192];  // [buf][128 rows][64 k]
    const int tid = threadIdx.x;
    // XCD-band swizzle (gridDim.y = 16, %8 == 0, bijective; z not in swizzle)
    const int id = blockIdx.y * gridDim.x + blockIdx.x;
    const int band = id & 7, within = id >> 3;
    const int rpb = gridDim.y >> 3; // 2
    const int by = band * rpb + (within % rpb);
    const int bx = within / rpb;
    const int m0 = by * 256, n0 = bx * 128;
    const int koff = blockIdx.z * K;
    const int wave = tid >> 6, lane = tid & 63;
    const int wr = wave >> 2, wc = wave & 3; // 2M x 4N wave grid, 32 cols/wave
    const int quad = lane >> 4, l16 = lane & 15;
    const int nkt = K >> 6;

    f32x4 acc[8][2] = {};

    auto stageA = [&](int kt, int half) {
        ushort_t* dst = &lds_a[kt & 1][half * 8192];
        const ushort_t* src = A + (size_t)(m0 + half * 128) * lda + koff + kt * 64;
#pragma unroll
        for (int it = 0; it < 2; ++it) {
            const int ci = it * 512 + tid;
            const int r = ci >> 3, c = ci & 7;
            async_copy16(src + (size_t)r * lda + ((c ^ (r & 7)) << 3), dst + ci * 8);
        }
    };
    auto stageB = [&](int kt) { // full 128x64 tile, 2 loads/thread
        ushort_t* dst = lds_b[kt & 1];
        const ushort_t* src = BT + (size_t)n0 * lda + koff + kt * 64;
#pragma unroll
        for (int it = 0; it < 2; ++it) {
            const int ci = it * 512 + tid;
            const int r = ci >> 3, c = ci & 7;
            async_copy16(src + (size_t)r * lda + ((c ^ (r & 7)) << 3), dst + ci * 8);
        }
    };

    stageA(0, 0); stageA(0, 1);
    stageB(0);
    stageB(1);
    asm volatile("s_waitcnt vmcnt(2)" ::: "memory"); // A(0)+B(0) landed; B(1) in flight
    __builtin_amdgcn_s_barrier();

    const int swz = l16 & 7;

#pragma unroll 1
    for (int kt = 0; kt < nkt; ++kt) {
        const int buf = kt & 1;
        const ushort_t* la = &lds_a[buf][wr * 8192]; // wave's 128-row A half
        const ushort_t* lb = lds_b[buf];
        const int brow = wc * 32;
        bf16x8 bfrag[2][2]; // [kk][fn], held across the 4 phases
#pragma unroll
        for (int p = 0; p < 4; ++p) {
            bf16x8 af[2][2]; // [sub-m][kk]
#pragma unroll
            for (int s = 0; s < 2; ++s) {
                const int r = (p * 2 + s) * 16 + l16;
#pragma unroll
                for (int kk = 0; kk < 2; ++kk)
                    af[s][kk] = *(const bf16x8*)&la[r * 64 + (((kk << 2) + quad) ^ swz) * 8];
            }
            if (p == 0) {
#pragma unroll
                for (int kk = 0; kk < 2; ++kk)
#pragma unroll
                    for (int fn = 0; fn < 2; ++fn) {
                        const int r = brow + fn * 16 + l16;
                        bfrag[kk][fn] = *(const bf16x8*)&lb[r * 64 + (((kk << 2) + quad) ^ swz) * 8];
                    }
            }
            if (p == 0) { if (kt + 1 < nkt) stageA(kt + 1, 0); }
            else if (p == 1) { if (kt + 1 < nkt) stageA(kt + 1, 1); }
            else if (p == 2) { if (kt + 2 < nkt) stageB(kt + 2); }

            __builtin_amdgcn_s_barrier();
            asm volatile("s_waitcnt lgkmcnt(0)" ::: "memory");
            __builtin_amdgcn_sched_barrier(0);
            __builtin_amdgcn_s_setprio(1);
#pragma unroll
            for (int s = 0; s < 2; ++s)
#pragma unroll
                for (int kk = 0; kk < 2; ++kk)
#pragma unroll
                    for (int fn = 0; fn < 2; ++fn)
                        acc[p * 2 + s][fn] = __builtin_amdgcn_mfma_f32_16x16x32_bf16(
                            af[s][kk], bfrag[kk][fn], acc[p * 2 + s][fn], 0, 0, 0);
            __builtin_amdgcn_s_setprio(0);
            if (p == 3) {
                if (kt + 2 < nkt) asm volatile("s_waitcnt vmcnt(2)" ::: "memory");
                else              asm volatile("s_waitcnt vmcnt(0)" ::: "memory");
            }
            __builtin_amdgcn_s_barrier();
        }
    }

    // ---- epilogue: bf16 partial to z-selected buffer (fm outer) ----
    ushort_t* pc = (blockIdx.z == 0) ? P0 : P1;
#pragma unroll
    for (int fm = 0; fm < 8; ++fm) {
        const int row_base = m0 + wr * 128 + fm * 16 + quad * 4;
#pragma unroll
        for (int fn = 0; fn < 2; ++fn) {
            const int col = n0 + wc * 32 + fn * 16 + l16;
#pragma unroll
            for (int r = 0; r < 4; ++r)
                pc[(size_t)(row_base + r) * N + col] = f2bf(acc[fm][fn][r]);
        }
    }
}

// ---------------- Flash attention (causal), MFMA, kt-parallel waves ----------
// O and l are linear in kt (no running max) => waves split (row-half wr,
// kt-stripe ws); K/V stream L2->registers; P in wave-private LDS; zero
// barriers in the k-loop; cross-stripe fp32 reduce once per phase.
__global__ __launch_bounds__(256, 2) void attn_flash(const ushort_t* __restrict__ qP,
                                                     const ushort_t* __restrict__ kP,
                                                     const ushort_t* __restrict__ vP,
                                                     ushort_t* __restrict__ o) {
    __shared__ __align__(16) ushort_t P_lds[4][32 * 72]; // wave-private [32 rows][72]
    __shared__ __align__(16) float Ored[2][32][68];      // per wr: partial O from ws=1
    __shared__ float Lred[2][32];                        // per wr: partial l from ws=1
    const int h = blockIdx.x, p = blockIdx.y, b = blockIdx.z; // h fastest (XCD affinity)
    const int bh = b * H_NUM + h;
    const int tid = threadIdx.x;
    const int wave = tid >> 6, lane = tid & 63;
    const int wr = wave >> 1, ws = wave & 1; // row-half, kt-stripe
    const int quad = lane >> 4, l16 = lane & 15;
    ushort_t* Pw = P_lds[wave];
    const ushort_t* kbase = kP + (size_t)bh * 32 * 4096;
    const ushort_t* vbase = vP + (size_t)bh * 32 * 4096;
    bf16x8 onesf;
#pragma unroll
    for (int j = 0; j < 8; ++j) onesf[j] = (__bf16)1.0f;

#pragma unroll 1
    for (int phase = 0; phase < 2; ++phase) {
        const int qt = (phase == 0) ? (31 - p) : p;
        const int nkt = qt + 1;
        const ushort_t* qbase = qP + ((size_t)bh * 32 + qt) * 4096;
        bf16x8 qf[2][2]; // [rowgroup][kk]
#pragma unroll
        for (int rg = 0; rg < 2; ++rg)
#pragma unroll
            for (int kk = 0; kk < 2; ++kk)
                qf[rg][kk] = *(const bf16x8*)&qbase[((kk * 4 + quad) * 64 + wr * 32 + rg * 16 + l16) * 8];
        f32x4 oacc[2][4] = {};
        f32x4 lacc[2] = {};
        __syncthreads(); // WAR: previous phase's epilogue reads of Ored/Lred done
        bf16x8 kf[8], vf[8];
        {
            const ushort_t* kb = kbase + (size_t)ws * 4096;
#pragma unroll
            for (int i = 0; i < 8; ++i)
                kf[i] = *(const bf16x8*)&kb[(((i >> 2) * 4 + quad) * 64 + (i & 3) * 16 + l16) * 8];
        }
#pragma unroll 1
        for (int kt = ws; kt < nkt; kt += 2) {
            f32x4 sacc[2][4] = {};
            __builtin_amdgcn_s_setprio(1);
#pragma unroll
            for (int kk = 0; kk < 2; ++kk)
#pragma unroll
                for (int kg = 0; kg < 4; ++kg)
#pragma unroll
                    for (int rg = 0; rg < 2; ++rg)
                        sacc[rg][kg] = __builtin_amdgcn_mfma_f32_16x16x32_bf16(
                            qf[rg][kk], kf[kk * 4 + kg], sacc[rg][kg], 0, 0, 0);
            __builtin_amdgcn_s_setprio(0);
            {
                const ushort_t* vb = vbase + (size_t)kt * 4096;
#pragma unroll
                for (int i = 0; i < 8; ++i)
                    vf[i] = *(const bf16x8*)&vb[(((i >> 2) * 4 + quad) * 64 + (i & 3) * 16 + l16) * 8];
            }
            if (kt + 2 < nkt) {
                const ushort_t* kb = kbase + (size_t)(kt + 2) * 4096;
#pragma unroll
                for (int i = 0; i < 8; ++i)
                    kf[i] = *(const bf16x8*)&kb[(((i >> 2) * 4 + quad) * 64 + (i & 3) * 16 + l16) * 8];
            }
#pragma unroll
            for (int rg = 0; rg < 2; ++rg)
#pragma unroll
                for (int kg = 0; kg < 4; ++kg) {
                    f32x4 sv = sacc[rg][kg];
                    if (kt == qt) { // wave-uniform branch
                        const int jc = kg * 16 + l16;
#pragma unroll
                        for (int r = 0; r < 4; ++r)
                            if (jc > wr * 32 + rg * 16 + quad * 4 + r) sv[r] = -3.0e38f;
                    }
#pragma unroll
                    for (int r = 0; r < 4; ++r) {
                        const float e = exp2f(sv[r]);
                        Pw[(rg * 16 + quad * 4 + r) * 72 + kg * 16 + l16] =
                            (ushort_t)(__float_as_uint(e) >> 16);
                    }
                }
            __builtin_amdgcn_s_setprio(1);
#pragma unroll
            for (int kk = 0; kk < 2; ++kk)
#pragma unroll
                for (int rg = 0; rg < 2; ++rg) {
                    bf16x8 pf = *(const bf16x8*)&Pw[(rg * 16 + l16) * 72 + kk * 32 + quad * 8];
                    lacc[rg] = __builtin_amdgcn_mfma_f32_16x16x32_bf16(pf, onesf, lacc[rg], 0, 0, 0);
#pragma unroll
                    for (int dg = 0; dg < 4; ++dg)
                        oacc[rg][dg] = __builtin_amdgcn_mfma_f32_16x16x32_bf16(
                            pf, vf[kk * 4 + dg], oacc[rg][dg], 0, 0, 0);
                }
            __builtin_amdgcn_s_setprio(0);
        }
        if (ws == 1) {
#pragma unroll
            for (int rg = 0; rg < 2; ++rg) {
#pragma unroll
                for (int dg = 0; dg < 4; ++dg)
#pragma unroll
                    for (int r = 0; r < 4; ++r)
                        Ored[wr][rg * 16 + quad * 4 + r][dg * 16 + l16] = oacc[rg][dg][r];
                if (l16 == 0) {
#pragma unroll
                    for (int r = 0; r < 4; ++r)
                        Lred[wr][rg * 16 + quad * 4 + r] = lacc[rg][r];
                }
            }
        }
        __syncthreads();
        if (ws == 0) {
#pragma unroll
            for (int rg = 0; rg < 2; ++rg)
#pragma unroll
                for (int r = 0; r < 4; ++r) {
                    const int rr = rg * 16 + quad * 4 + r;
                    const float inv = 1.0f / (lacc[rg][r] + Lred[wr][rr]);
                    const int trow = qt * 64 + wr * 32 + rr;
#pragma unroll
                    for (int dg = 0; dg < 4; ++dg) {
                        const float v = oacc[rg][dg][r] + Ored[wr][rr][dg * 16 + l16];
                        o[(size_t)(b * T_SEQ + trow) * E_DIM + h * HD_DIM + dg * 16 + l16] =
                            f2bf(v * inv);
                    }
                }
        }
    }
}

// ---------------- Host launcher ----------------
extern "C" void kernel_launch(void* const* d_in, const int* in_sizes, int n_in,
                              void* d_out, int out_size, void* d_ws, size_t ws_size,
                              hipStream_t stream) {
    const float* x = (const float*)d_in[0];
    const float* Wq = (const float*)d_in[1];
    const float* Wk = (const float*)d_in[2];
    const float* Wv = (const float*)d_in[3];
    const float* Wproj = (const float*)d_in[4];
    const float* bproj = (const float*)d_in[5];
    const float* W1 = (const float*)d_in[6];
    const float* b1 = (const float*)d_in[7];
    const float* W2 = (const float*)d_in[8];
    const float* b2 = (const float*)d_in[9];
    const float* g1 = (const float*)d_in[10];
    const float* be1 = (const float*)d_in[11];
    const float* g2 = (const float*)d_in[12];
    const float* be2 = (const float*)d_in[13];

    // Workspace layout (80 MB, lifetime-overlapped):
    //  [0,8)    W2T bf16              setup -> FFN2
    //  [8,24)   x1 fp32               reduce_ln -> reduce_out
    //  [24,32)  W1T bf16              setup -> FFN1;  then FFN2 partial fp1 @24
    //  [32,34)  WprojT bf16           setup -> proj
    //  [34,42)  hln/ocat bf16         hln: LN1->QKV; ocat: attn->proj
    //  [42,48)  WqkvT bf16            setup -> QKV
    //  [48,72)  qP/kP/vP bf16 packed  QKV -> attn;  then proj partials pp0@48 pp1@56
    //  [72,80)  h2 bf16               reduce_ln -> FFN1
    //  f1 bf16 32MB @34 [34,66)      FFN1 -> FFN2 (overlays hln/WqkvT/qP/kP/vP-head)
    //  FFN2 partials: fp0 @66 [66,74), fp1 @24 [24,32)  (FFN2 -> reduce_out)
    char* ws = (char*)d_ws;
    const size_t MB = 1024 * 1024;
    ushort_t* W2T    = (ushort_t*)(ws + 0 * MB);
    float*    x1     = (float*)   (ws + 8 * MB);
    ushort_t* W1T    = (ushort_t*)(ws + 24 * MB);
    ushort_t* WprojT = (ushort_t*)(ws + 32 * MB);
    ushort_t* hln    = (ushort_t*)(ws + 34 * MB);
    ushort_t* ocat   = hln;
    ushort_t* WqkvT  = (ushort_t*)(ws + 42 * MB);
    ushort_t* qP     = (ushort_t*)(ws + 48 * MB);
    ushort_t* kP     = (ushort_t*)(ws + 56 * MB);
    ushort_t* vP     = (ushort_t*)(ws + 64 * MB);
    ushort_t* h2     = (ushort_t*)(ws + 72 * MB);
    ushort_t* f1     = (ushort_t*)(ws + 34 * MB);
    ushort_t* pp0    = (ushort_t*)(ws + 48 * MB); // proj partial z=0 (over qP)
    ushort_t* pp1    = (ushort_t*)(ws + 56 * MB); // proj partial z=1 (over kP)
    ushort_t* fp0    = (ushort_t*)(ws + 66 * MB); // FFN2 partial z=0
    ushort_t* fp1    = (ushort_t*)(ws + 24 * MB); // FFN2 partial z=1 (over W1T)
    (void)ws_size; (void)in_sizes; (void)n_in; (void)out_size;

    // All four weight transposes in one launch
    transpose_all_kernel<<<12288, dim3(32, 8, 1), 0, stream>>>(
        Wq, Wk, Wv, Wproj, W1, W2, WqkvT, WprojT, W1T, W2T);

    ln_kernel<<<N_TOK, 256, 0, stream>>>(x, g1, be1, hln);
    // QKV: 256x192 8-phase, grid 16x16 = 256 blocks full fill
    gemm192_qkv<<<dim3(16, 16), 512, 0, stream>>>(hln, WqkvT, qP, kP, vP, E_DIM, E_DIM);
    // h fastest -> id%8 = h%8 -> per-XCD K/V working set 2 MB (L2-resident)
    attn_flash<<<dim3(16, 16, 2), 256, 0, stream>>>(qP, kP, vP, ocat);
    // proj split-K=2: 256x128 8-phase (8x16x2 = 256 blocks full fill, K-slice 512)
    gemm128n<<<dim3(8, 16, 2), 512, 0, stream>>>(ocat, WprojT, pp0, pp1,
                                                 E_DIM, 512, E_DIM);
    // fused: x1 = x + bproj + pp0 + pp1 ; h2 = LN2(x1)
    reduce_ln_kernel<<<N_TOK, 256, 0, stream>>>(pp0, pp1, x, bproj, g2, be2, x1, h2);
    // FFN1 + bias + relu -> f1 bf16: 256x256 8-phase kernel (256 blocks = 1/CU)
    gemm256_ffn1<<<dim3(16, 16), 512, 0, stream>>>(h2, W1T, b1, f1, FF_DIM, E_DIM, E_DIM);
    // FFN2 split-K=2: 256x128 8-phase (8x16x2 = 256 blocks full fill, K-slice 2048)
    // (r7: was 2-phase gemm_bt<3,64> @ 48.6us / 707 TF)
    gemm128n<<<dim3(8, 16, 2), 512, 0, stream>>>(f1, W2T, fp0, fp1,
                                                 E_DIM, 2048, FF_DIM);
    // d_out = x1 + b2 + fp0 + fp1
    reduce_out_kernel<<<N_TOK, 256, 0, stream>>>(fp0, fp1, x1, b2, (float*)d_out);
}

// Round 8
// 314.352 us; speedup vs baseline: 1.0420x; 1.0420x over previous
//
#include <hip/hip_runtime.h>
#include <hip/hip_bf16.h>
#include <stdint.h>

// Problem constants (B,T,E,H,HD,FF) = (2,2048,1024,16,64,4096).
// I/O dtype: float32. Internal GEMM/attention compute: bf16 MFMA, fp32 accumulate.
#define T_SEQ 2048
#define E_DIM 1024
#define H_NUM 16
#define HD_DIM 64
#define FF_DIM 4096
#define B_NUM 2
#define N_TOK (B_NUM * T_SEQ) // 4096 token rows

typedef unsigned short ushort_t;
typedef __bf16 bf16x8 __attribute__((ext_vector_type(8)));
typedef float f32x4 __attribute__((ext_vector_type(4)));

__device__ __forceinline__ float bf2f(ushort_t u) {
    return __uint_as_float(((unsigned)u) << 16);
}
__device__ __forceinline__ ushort_t f2bf(float f) {
    unsigned u = __float_as_uint(f);
    u += 0x7fffu + ((u >> 16) & 1u);   // round-to-nearest-even
    return (ushort_t)(u >> 16);
}
__device__ __forceinline__ float bflo(unsigned u) { return __uint_as_float(u << 16); }
__device__ __forceinline__ float bfhi(unsigned u) { return __uint_as_float(u & 0xffff0000u); }

// Async global->LDS, 16B per lane. LDS dst is wave-uniform base + lane*16 in
// issue order -> LDS image layout is contiguous in ci order.
__device__ __forceinline__ void async_copy16(const ushort_t* g, ushort_t* l) {
    __builtin_amdgcn_global_load_lds(
        (__attribute__((address_space(1))) uint32_t*)(ushort_t*)g,
        (__attribute__((address_space(3))) uint32_t*)l, 16, 0, 0);
}

// ---------------- LayerNorm: one block per row of 1024; fp32 in, bf16 out ----
__global__ __launch_bounds__(256) void ln_kernel(const float* __restrict__ x,
                                                 const float* __restrict__ g,
                                                 const float* __restrict__ be,
                                                 ushort_t* __restrict__ out) {
    __shared__ float red[8];
    const int row = blockIdx.x, tid = threadIdx.x;
    const float* xr = x + (size_t)row * E_DIM;
    float4 v = ((const float4*)xr)[tid];   // 4 fp32 per thread
    float s = v.x + v.y + v.z + v.w;
    float sq = v.x * v.x + v.y * v.y + v.z * v.z + v.w * v.w;
    for (int off = 32; off; off >>= 1) {
        s += __shfl_xor(s, off);
        sq += __shfl_xor(sq, off);
    }
    const int wid = tid >> 6, lane = tid & 63;
    if (lane == 0) { red[wid] = s; red[4 + wid] = sq; }
    __syncthreads();
    s = red[0] + red[1] + red[2] + red[3];
    sq = red[4] + red[5] + red[6] + red[7];
    const float mean = s * (1.0f / E_DIM);
    const float var = sq * (1.0f / E_DIM) - mean * mean;
    const float rstd = rsqrtf(var + 1e-5f);
    float4 gv = ((const float4*)g)[tid];
    float4 bv = ((const float4*)be)[tid];
    unsigned o0 = f2bf((v.x - mean) * rstd * gv.x + bv.x);
    unsigned o1 = f2bf((v.y - mean) * rstd * gv.y + bv.y);
    unsigned o2 = f2bf((v.z - mean) * rstd * gv.z + bv.z);
    unsigned o3 = f2bf((v.w - mean) * rstd * gv.w + bv.w);
    uint2 w;
    w.x = o0 | (o1 << 16);
    w.y = o2 | (o3 << 16);
    ((uint2*)(out + (size_t)row * E_DIM))[tid] = w;
}

// ---- proj split-K reduce + residual + LN2 fused: one block per token row ----
// v = x + bproj + p0 + p1 ; x1 = v (fp32) ; h2 = LN(v)*g2+be2 (bf16)
__global__ __launch_bounds__(256) void reduce_ln_kernel(const ushort_t* __restrict__ p0,
                                                        const ushort_t* __restrict__ p1,
                                                        const float* __restrict__ x,
                                                        const float* __restrict__ bias,
                                                        const float* __restrict__ g,
                                                        const float* __restrict__ be,
                                                        float* __restrict__ x1,
                                                        ushort_t* __restrict__ h2) {
    __shared__ float red[8];
    const int row = blockIdx.x, tid = threadIdx.x;
    uint2 u0 = ((const uint2*)(p0 + (size_t)row * E_DIM))[tid];
    uint2 u1 = ((const uint2*)(p1 + (size_t)row * E_DIM))[tid];
    float4 xv = ((const float4*)(x + (size_t)row * E_DIM))[tid];
    float4 bv = ((const float4*)bias)[tid];
    float4 v;
    v.x = xv.x + bv.x + bflo(u0.x) + bflo(u1.x);
    v.y = xv.y + bv.y + bfhi(u0.x) + bfhi(u1.x);
    v.z = xv.z + bv.z + bflo(u0.y) + bflo(u1.y);
    v.w = xv.w + bv.w + bfhi(u0.y) + bfhi(u1.y);
    ((float4*)(x1 + (size_t)row * E_DIM))[tid] = v;
    float s = v.x + v.y + v.z + v.w;
    float sq = v.x * v.x + v.y * v.y + v.z * v.z + v.w * v.w;
    for (int off = 32; off; off >>= 1) {
        s += __shfl_xor(s, off);
        sq += __shfl_xor(sq, off);
    }
    const int wid = tid >> 6, lane = tid & 63;
    if (lane == 0) { red[wid] = s; red[4 + wid] = sq; }
    __syncthreads();
    s = red[0] + red[1] + red[2] + red[3];
    sq = red[4] + red[5] + red[6] + red[7];
    const float mean = s * (1.0f / E_DIM);
    const float var = sq * (1.0f / E_DIM) - mean * mean;
    const float rstd = rsqrtf(var + 1e-5f);
    float4 gv = ((const float4*)g)[tid];
    float4 ev = ((const float4*)be)[tid];
    unsigned o0 = f2bf((v.x - mean) * rstd * gv.x + ev.x);
    unsigned o1 = f2bf((v.y - mean) * rstd * gv.y + ev.y);
    unsigned o2 = f2bf((v.z - mean) * rstd * gv.z + ev.z);
    unsigned o3 = f2bf((v.w - mean) * rstd * gv.w + ev.w);
    uint2 w;
    w.x = o0 | (o1 << 16);
    w.y = o2 | (o3 << 16);
    ((uint2*)(h2 + (size_t)row * E_DIM))[tid] = w;
}

// ---- FFN2 split-K reduce + bias + residual: d_out = x1 + b2 + p0 + p1 ------
__global__ __launch_bounds__(256) void reduce_out_kernel(const ushort_t* __restrict__ p0,
                                                         const ushort_t* __restrict__ p1,
                                                         const float* __restrict__ x1,
                                                         const float* __restrict__ bias,
                                                         float* __restrict__ out) {
    const int row = blockIdx.x, tid = threadIdx.x;
    uint2 u0 = ((const uint2*)(p0 + (size_t)row * E_DIM))[tid];
    uint2 u1 = ((const uint2*)(p1 + (size_t)row * E_DIM))[tid];
    float4 xv = ((const float4*)(x1 + (size_t)row * E_DIM))[tid];
    float4 bv = ((const float4*)bias)[tid];
    float4 v;
    v.x = xv.x + bv.x + bflo(u0.x) + bflo(u1.x);
    v.y = xv.y + bv.y + bfhi(u0.x) + bfhi(u1.x);
    v.z = xv.z + bv.z + bflo(u0.y) + bflo(u1.y);
    v.w = xv.w + bv.w + bfhi(u0.y) + bfhi(u1.y);
    ((float4*)(out + (size_t)row * E_DIM))[tid] = v;
}

// -------- Merged convert-transposes (fp32 weights -> bf16 B^T layouts) -------
//   [0,3072)      Wq/Wk/Wv [H][1024][64] -> WqkvT rows (mat*1024+h*64+d) over E
//   [3072,4096)   Wproj 1024x1024 -> WprojT
//   [4096,8192)   W1 1024x4096 -> W1T
//   [8192,12288)  W2 4096x1024 -> W2T
__global__ __launch_bounds__(256) void transpose_all_kernel(const float* __restrict__ Wq,
                                                            const float* __restrict__ Wk,
                                                            const float* __restrict__ Wv,
                                                            const float* __restrict__ Wproj,
                                                            const float* __restrict__ W1,
                                                            const float* __restrict__ W2,
                                                            ushort_t* __restrict__ WqkvT,
                                                            ushort_t* __restrict__ WprojT,
                                                            ushort_t* __restrict__ W1T,
                                                            ushort_t* __restrict__ W2T) {
    __shared__ ushort_t tile[32][33];
    const int id = blockIdx.x;
    const float* in;
    ushort_t* out;
    int R, C, r0, c0;
    if (id < 3072) {
        const int z = id >> 6, rem = id & 63;   // z: 3 mats x 16 heads
        const int m = z >> 4, hh = z & 15;
        in = ((m == 0) ? Wq : ((m == 1) ? Wk : Wv)) + (size_t)hh * E_DIM * HD_DIM; // [1024][64]
        out = WqkvT + (size_t)(m * E_DIM + hh * HD_DIM) * E_DIM;
        R = E_DIM; C = HD_DIM;
        c0 = (rem & 1) * 32; r0 = (rem >> 1) * 32;
    } else if (id < 4096) {
        const int i = id - 3072;
        in = Wproj; out = WprojT; R = E_DIM; C = E_DIM;
        c0 = (i & 31) * 32; r0 = (i >> 5) * 32;
    } else if (id < 8192) {
        const int i = id - 4096;
        in = W1; out = W1T; R = E_DIM; C = FF_DIM;
        c0 = (i & 127) * 32; r0 = (i >> 7) * 32;
    } else {
        const int i = id - 8192;
        in = W2; out = W2T; R = FF_DIM; C = E_DIM;
        c0 = (i & 31) * 32; r0 = (i >> 5) * 32;
    }
    const int tx = threadIdx.x, ty = threadIdx.y;
#pragma unroll
    for (int i = 0; i < 32; i += 8) tile[ty + i][tx] = f2bf(in[(size_t)(r0 + ty + i) * C + (c0 + tx)]);
    __syncthreads();
#pragma unroll
    for (int i = 0; i < 32; i += 8) out[(size_t)(c0 + ty + i) * R + (r0 + tx)] = tile[tx][ty + i];
}

// ---------------- 256x256 8-phase GEMM (T2+T3+T4+T5), FFN1 ------------------
// Grid (N/256, M/256), 512 thr, 8 waves 2Mx4N; per-wave C = 128x64 (8x4
// frags). BK=64, double-buffered 128 KiB LDS, half-tile (128 rows x 64 k)
// staging granularity. Schedule per K-tile kt (4 phases; phase p computes
// m-pair {2p,2p+1} x K=64):
//   phase: { ds-read A-frags (+all 8 B-frags at p0); stage ONE half-tile;
//            s_barrier; lgkmcnt(0); setprio(1); 16 MFMA; setprio(0);
//            [p3: counted vmcnt(4)]; s_barrier }
// Stage targets: p0/p1: A-halves(kt+1)->buf^1; p2/p3: B-halves(kt+2)->buf.
// vmcnt(4) at p3 keeps B(kt+2)'s 4 loads in flight across the tile boundary;
// A(kt+1)+B(kt+1) guaranteed landed for kt+1 p0.
// LDS XOR swizzle (T2): 16B chunk' = chunk ^ (row&7) on global src + ds_read
// addr (rule #21). r1 measured: BANK_CONFLICT 4.19M->0. Epilogue fm-outer
// (r2 verified: no partial-line L2 writeback amplification).
__global__ __launch_bounds__(512, 2) void gemm256_ffn1(const ushort_t* __restrict__ A,
                                                       const ushort_t* __restrict__ BT,
                                                       const float* __restrict__ bias,
                                                       ushort_t* __restrict__ C,
                                                       int N, int K, int lda) {
    __shared__ __align__(16) ushort_t lds_a[2][16384]; // [buf][half:2][128 rows][64 k]
    __shared__ __align__(16) ushort_t lds_b[2][16384];
    const int tid = threadIdx.x;
    // XCD-band swizzle (gridDim.y % 8 == 0; bijective since gy%8==0)
    const int id = blockIdx.y * gridDim.x + blockIdx.x;
    const int band = id & 7, within = id >> 3;
    const int rpb = gridDim.y >> 3;
    const int by = band * rpb + (within % rpb);
    const int bx = within / rpb;
    const int m0 = by * 256, n0 = bx * 256;
    const int wave = tid >> 6, lane = tid & 63;
    const int wr = wave >> 2, wc = wave & 3; // 2M x 4N wave grid
    const int quad = lane >> 4, l16 = lane & 15;
    const int nkt = K >> 6;

    f32x4 acc[8][4] = {};

    auto stageA = [&](int kt, int half) {
        ushort_t* dst = &lds_a[kt & 1][half * 8192];
        const ushort_t* src = A + (size_t)(m0 + half * 128) * lda + kt * 64;
#pragma unroll
        for (int it = 0; it < 2; ++it) {
            const int ci = it * 512 + tid;
            const int r = ci >> 3, c = ci & 7;
            async_copy16(src + (size_t)r * lda + ((c ^ (r & 7)) << 3), dst + ci * 8);
        }
    };
    auto stageB = [&](int kt, int half) {
        ushort_t* dst = &lds_b[kt & 1][half * 8192];
        const ushort_t* src = BT + (size_t)(n0 + half * 128) * lda + kt * 64;
#pragma unroll
        for (int it = 0; it < 2; ++it) {
            const int ci = it * 512 + tid;
            const int r = ci >> 3, c = ci & 7;
            async_copy16(src + (size_t)r * lda + ((c ^ (r & 7)) << 3), dst + ci * 8);
        }
    };

    // Prologue: A(0), B(0), B(1). A(1) comes in kt=0 phases 0-1 (steady state).
    stageA(0, 0); stageA(0, 1);
    stageB(0, 0); stageB(0, 1);
    stageB(1, 0); stageB(1, 1);
    asm volatile("s_waitcnt vmcnt(4)" ::: "memory"); // A(0)+B(0) landed; B(1) in flight
    __builtin_amdgcn_s_barrier();

    const int swz = l16 & 7; // row&7 for all this lane's fragment rows

#pragma unroll 1
    for (int kt = 0; kt < nkt; ++kt) {
        const int buf = kt & 1;
        const ushort_t* la = &lds_a[buf][wr * 8192];           // wave's A half
        const ushort_t* lb = &lds_b[buf][(wc >> 1) * 8192];    // wave's B half
        const int brow = (wc & 1) * 64;
        bf16x8 bfrag[2][4]; // [kk][fn], held across the 4 phases
#pragma unroll
        for (int p = 0; p < 4; ++p) {
            bf16x8 af[2][2]; // [sub-m][kk]
#pragma unroll
            for (int s = 0; s < 2; ++s) {
                const int r = (p * 2 + s) * 16 + l16;
#pragma unroll
                for (int kk = 0; kk < 2; ++kk)
                    af[s][kk] = *(const bf16x8*)&la[r * 64 + (((kk << 2) + quad) ^ swz) * 8];
            }
            if (p == 0) {
#pragma unroll
                for (int kk = 0; kk < 2; ++kk)
#pragma unroll
                    for (int fn = 0; fn < 4; ++fn) {
                        const int r = brow + fn * 16 + l16;
                        bfrag[kk][fn] = *(const bf16x8*)&lb[r * 64 + (((kk << 2) + quad) ^ swz) * 8];
                    }
            }
            if (p == 0) { if (kt + 1 < nkt) stageA(kt + 1, 0); }
            else if (p == 1) { if (kt + 1 < nkt) stageA(kt + 1, 1); }
            else if (p == 2) { if (kt + 2 < nkt) stageB(kt + 2, 0); }
            else { if (kt + 2 < nkt) stageB(kt + 2, 1); }

            __builtin_amdgcn_s_barrier();
            asm volatile("s_waitcnt lgkmcnt(0)" ::: "memory");
            __builtin_amdgcn_sched_barrier(0);
            __builtin_amdgcn_s_setprio(1);
#pragma unroll
            for (int s = 0; s < 2; ++s)
#pragma unroll
                for (int kk = 0; kk < 2; ++kk)
#pragma unroll
                    for (int fn = 0; fn < 4; ++fn)
                        acc[p * 2 + s][fn] = __builtin_amdgcn_mfma_f32_16x16x32_bf16(
                            af[s][kk], bfrag[kk][fn], acc[p * 2 + s][fn], 0, 0, 0);
            __builtin_amdgcn_s_setprio(0);
            if (p == 3) {
                if (kt + 2 < nkt) asm volatile("s_waitcnt vmcnt(4)" ::: "memory");
                else              asm volatile("s_waitcnt vmcnt(0)" ::: "memory");
            }
            __builtin_amdgcn_s_barrier();
        }
    }

    // ---- epilogue: relu(acc + bias) -> bf16 (fm outer: dense row spans) ----
#pragma unroll
    for (int fm = 0; fm < 8; ++fm) {
        const int row_base = m0 + wr * 128 + fm * 16 + quad * 4;
#pragma unroll
        for (int fn = 0; fn < 4; ++fn) {
            const int col = n0 + wc * 64 + fn * 16 + l16;
            const float bv = bias[col];
#pragma unroll
            for (int r = 0; r < 4; ++r)
                C[(size_t)(row_base + r) * N + col] =
                    f2bf(fmaxf(acc[fm][fn][r] + bv, 0.0f));
        }
    }
}

// ------------- 256x192 8-phase GEMM for QKV (full 256-block fill) -----------
// N=3072 -> BN=192: grid 16x16 = 256 blocks = 1/CU full fill. Per-wave C =
// 128x48 (8x3 frags), 12 MFMA/phase. LDS = A 64KB + B 48KB = 112KB.
// B staged as ONE full 192x64 tile (3 loads/thread) at p2; A halves at p0/p1.
// vmcnt ledger: at p3 outstanding = B(kt+1)[3]+A(kt+1)[4]+B(kt+2)[3] = 10;
// vmcnt(3) leaves exactly B(kt+2) in flight. Prologue: 10 loads, vmcnt(3).
// Scatter epilogue = verified ideal 24.6MB WRITE mapping, fm-outer.
__global__ __launch_bounds__(512, 2) void gemm192_qkv(const ushort_t* __restrict__ A,
                                                      const ushort_t* __restrict__ BT,
                                                      ushort_t* __restrict__ qP,
                                                      ushort_t* __restrict__ kP,
                                                      ushort_t* __restrict__ vP,
                                                      int K, int lda) {
    __shared__ __align__(16) ushort_t lds_a[2][16384]; // [buf][half:2][128 rows][64 k]
    __shared__ __align__(16) ushort_t lds_b[2][12288]; // [buf][192 rows][64 k]
    const int tid = threadIdx.x;
    const int id = blockIdx.y * gridDim.x + blockIdx.x;
    const int band = id & 7, within = id >> 3;
    const int rpb = gridDim.y >> 3; // 2
    const int by = band * rpb + (within % rpb);
    const int bx = within / rpb;
    const int m0 = by * 256, n0 = bx * 192;
    const int wave = tid >> 6, lane = tid & 63;
    const int wr = wave >> 2, wc = wave & 3; // 2M x 4N wave grid, 48 cols/wave
    const int quad = lane >> 4, l16 = lane & 15;
    const int nkt = K >> 6;

    f32x4 acc[8][3] = {};

    auto stageA = [&](int kt, int half) {
        ushort_t* dst = &lds_a[kt & 1][half * 8192];
        const ushort_t* src = A + (size_t)(m0 + half * 128) * lda + kt * 64;
#pragma unroll
        for (int it = 0; it < 2; ++it) {
            const int ci = it * 512 + tid;
            const int r = ci >> 3, c = ci & 7;
            async_copy16(src + (size_t)r * lda + ((c ^ (r & 7)) << 3), dst + ci * 8);
        }
    };
    auto stageB = [&](int kt) { // full 192x64 tile, 3 loads/thread
        ushort_t* dst = lds_b[kt & 1];
        const ushort_t* src = BT + (size_t)n0 * lda + kt * 64;
#pragma unroll
        for (int it = 0; it < 3; ++it) {
            const int ci = it * 512 + tid;
            const int r = ci >> 3, c = ci & 7;
            async_copy16(src + (size_t)r * lda + ((c ^ (r & 7)) << 3), dst + ci * 8);
        }
    };

    stageA(0, 0); stageA(0, 1);
    stageB(0);
    stageB(1);
    asm volatile("s_waitcnt vmcnt(3)" ::: "memory"); // A(0)+B(0) landed; B(1) in flight
    __builtin_amdgcn_s_barrier();

    const int swz = l16 & 7;

#pragma unroll 1
    for (int kt = 0; kt < nkt; ++kt) {
        const int buf = kt & 1;
        const ushort_t* la = &lds_a[buf][wr * 8192]; // wave's 128-row A half
        const ushort_t* lb = lds_b[buf];
        const int brow = wc * 48;
        bf16x8 bfrag[2][3]; // [kk][fn], held across the 4 phases
#pragma unroll
        for (int p = 0; p < 4; ++p) {
            bf16x8 af[2][2]; // [sub-m][kk]
#pragma unroll
            for (int s = 0; s < 2; ++s) {
                const int r = (p * 2 + s) * 16 + l16;
#pragma unroll
                for (int kk = 0; kk < 2; ++kk)
                    af[s][kk] = *(const bf16x8*)&la[r * 64 + (((kk << 2) + quad) ^ swz) * 8];
            }
            if (p == 0) {
#pragma unroll
                for (int kk = 0; kk < 2; ++kk)
#pragma unroll
                    for (int fn = 0; fn < 3; ++fn) {
                        const int r = brow + fn * 16 + l16;
                        bfrag[kk][fn] = *(const bf16x8*)&lb[r * 64 + (((kk << 2) + quad) ^ swz) * 8];
                    }
            }
            if (p == 0) { if (kt + 1 < nkt) stageA(kt + 1, 0); }
            else if (p == 1) { if (kt + 1 < nkt) stageA(kt + 1, 1); }
            else if (p == 2) { if (kt + 2 < nkt) stageB(kt + 2); }

            __builtin_amdgcn_s_barrier();
            asm volatile("s_waitcnt lgkmcnt(0)" ::: "memory");
            __builtin_amdgcn_sched_barrier(0);
            __builtin_amdgcn_s_setprio(1);
#pragma unroll
            for (int s = 0; s < 2; ++s)
#pragma unroll
                for (int kk = 0; kk < 2; ++kk)
#pragma unroll
                    for (int fn = 0; fn < 3; ++fn)
                        acc[p * 2 + s][fn] = __builtin_amdgcn_mfma_f32_16x16x32_bf16(
                            af[s][kk], bfrag[kk][fn], acc[p * 2 + s][fn], 0, 0, 0);
            __builtin_amdgcn_s_setprio(0);
            if (p == 3) {
                if (kt + 2 < nkt) asm volatile("s_waitcnt vmcnt(3)" ::: "memory");
                else              asm volatile("s_waitcnt vmcnt(0)" ::: "memory");
            }
            __builtin_amdgcn_s_barrier();
        }
    }

    // ---- scatter epilogue (fm outer) ----
#pragma unroll
    for (int fm = 0; fm < 8; ++fm) {
        const int row_base = m0 + wr * 128 + fm * 16 + quad * 4;
#pragma unroll
        for (int fn = 0; fn < 3; ++fn) {
            const int col = n0 + wc * 48 + fn * 16 + l16; // [0,3072)
            const int mat = col >> 10, c = col & 1023, hh = c >> 6, d = c & 63;
#pragma unroll
            for (int r = 0; r < 4; ++r) {
                const int row = row_base + r;
                const int bb = row >> 11, tt = row & 2047;
                const int bh = bb * H_NUM + hh;
                float v = acc[fm][fn][r];
                size_t idx;
                ushort_t* dst;
                if (mat == 0) {        // qP [bh][qt:32][ch:8][row:64][8], pre-scaled
                    idx = ((((size_t)bh * 32 + (tt >> 6)) * 8 + (d >> 3)) * 64 + (tt & 63)) * 8 + (d & 7);
                    dst = qP;
                    v *= 0.0450842048f; // E^-0.5 * log2(e): softmax runs in exp2 domain
                } else if (mat == 1) { // kP [bh][kt:32][ch:8][key:64][8]
                    idx = ((((size_t)bh * 32 + (tt >> 6)) * 8 + (d >> 3)) * 64 + (tt & 63)) * 8 + (d & 7);
                    dst = kP;
                } else {               // vP [bh][kt:32][kh:8][d:64][8]  (V transposed)
                    idx = ((((size_t)bh * 32 + (tt >> 6)) * 8 + ((tt & 63) >> 3)) * 64 + d) * 8 + (tt & 7);
                    dst = vP;
                }
                dst[idx] = f2bf(v);
            }
        }
    }
}

// ------------- 256x128 THICK-phase split-K GEMM (proj + FFN2) ---------------
// r7 post-mortem: the 4-phase/8-MFMA variant REGRESSED (53.1us vs 2-phase's
// 48.6): at 8 MFMA/phase the fixed per-phase cost (2 barriers + lgkmcnt
// drain) doesn't amortize. r8 fix: 2 phases per K-tile, 16 MFMA/phase --
// the exact MFMA density of the proven gemm256_ffn1 template.
// Grid (N/128, M/256, 2): 256 blocks full fill. Per-wave C = 128x32
// (8x2 frags). LDS = A 64KB + B 32KB = 96KB -> 1 block/CU.
// Phase h of kt computes m-subrows 4h..4h+3 x 2kk x 2fn = 16 MFMA.
// Staging: p0 = BOTH A-halves(kt+1) -> buf^1 (4 loads/thr);
//          p1 = B(kt+2) full 128x64 tile -> buf (2 loads/thr).
// Liveness: A(buf^1) last read kt-1 p1 (barrier separates); B(buf) last
// read kt p0 (barrier separates).
// vmcnt ledger (steady state at p1 end): outstanding = B(kt+1)[2] +
// A(kt+1)[4] + B(kt+2)[2] = 8 -> vmcnt(2) leaves exactly B(kt+2) in
// flight; A(kt+1)+B(kt+1) landed for kt+1 p0. Prologue: A(0)h0,h1 + B(0)
// + B(1) = 8 loads; vmcnt(2). Tail kt+2>=nkt -> vmcnt(0).
__global__ __launch_bounds__(512, 2) void gemm128n(const ushort_t* __restrict__ A,
                                                   const ushort_t* __restrict__ BT,
                                                   ushort_t* __restrict__ P0,
                                                   ushort_t* __restrict__ P1,
                                                   int N, int K, int lda) {
    __shared__ __align__(16) ushort_t lds_a[2][16384]; // [buf][half:2][128 rows][64 k]
    __shared__ __align__(16) ushort_t lds_b[2][8192];  // [buf][128 rows][64 k]
    const int tid = threadIdx.x;
    // XCD-band swizzle (gridDim.y = 16, %8 == 0, bijective; z not in swizzle)
    const int id = blockIdx.y * gridDim.x + blockIdx.x;
    const int band = id & 7, within = id >> 3;
    const int rpb = gridDim.y >> 3; // 2
    const int by = band * rpb + (within % rpb);
    const int bx = within / rpb;
    const int m0 = by * 256, n0 = bx * 128;
    const int koff = blockIdx.z * K;
    const int wave = tid >> 6, lane = tid & 63;
    const int wr = wave >> 2, wc = wave & 3; // 2M x 4N wave grid, 32 cols/wave
    const int quad = lane >> 4, l16 = lane & 15;
    const int nkt = K >> 6;

    f32x4 acc[8][2] = {};

    auto stageA = [&](int kt, int half) {
        ushort_t* dst = &lds_a[kt & 1][half * 8192];
        const ushort_t* src = A + (size_t)(m0 + half * 128) * lda + koff + kt * 64;
#pragma unroll
        for (int it = 0; it < 2; ++it) {
            const int ci = it * 512 + tid;
            const int r = ci >> 3, c = ci & 7;
            async_copy16(src + (size_t)r * lda + ((c ^ (r & 7)) << 3), dst + ci * 8);
        }
    };
    auto stageB = [&](int kt) { // full 128x64 tile, 2 loads/thread
        ushort_t* dst = lds_b[kt & 1];
        const ushort_t* src = BT + (size_t)n0 * lda + koff + kt * 64;
#pragma unroll
        for (int it = 0; it < 2; ++it) {
            const int ci = it * 512 + tid;
            const int r = ci >> 3, c = ci & 7;
            async_copy16(src + (size_t)r * lda + ((c ^ (r & 7)) << 3), dst + ci * 8);
        }
    };

    stageA(0, 0); stageA(0, 1);
    stageB(0);
    stageB(1);
    asm volatile("s_waitcnt vmcnt(2)" ::: "memory"); // A(0)+B(0) landed; B(1) in flight
    __builtin_amdgcn_s_barrier();

    const int swz = l16 & 7;

#pragma unroll 1
    for (int kt = 0; kt < nkt; ++kt) {
        const int buf = kt & 1;
        const ushort_t* la = &lds_a[buf][wr * 8192]; // wave's 128-row A half
        const ushort_t* lb = lds_b[buf];
        const int brow = wc * 32;
        bf16x8 bfrag[2][2]; // [kk][fn], held across both phases
#pragma unroll
        for (int h = 0; h < 2; ++h) {
            // ---- ds-reads for this phase: 4 m-subrows x 2 kk ----
            bf16x8 af[4][2];
#pragma unroll
            for (int s = 0; s < 4; ++s) {
                const int r = (h * 4 + s) * 16 + l16;
#pragma unroll
                for (int kk = 0; kk < 2; ++kk)
                    af[s][kk] = *(const bf16x8*)&la[r * 64 + (((kk << 2) + quad) ^ swz) * 8];
            }
            if (h == 0) {
#pragma unroll
                for (int kk = 0; kk < 2; ++kk)
#pragma unroll
                    for (int fn = 0; fn < 2; ++fn) {
                        const int r = brow + fn * 16 + l16;
                        bfrag[kk][fn] = *(const bf16x8*)&lb[r * 64 + (((kk << 2) + quad) ^ swz) * 8];
                    }
            }
            // ---- staging: p0 = both A halves(kt+1); p1 = B(kt+2) ----
            if (h == 0) {
                if (kt + 1 < nkt) { stageA(kt + 1, 0); stageA(kt + 1, 1); }
            } else {
                if (kt + 2 < nkt) stageB(kt + 2);
            }

            __builtin_amdgcn_s_barrier();
            asm volatile("s_waitcnt lgkmcnt(0)" ::: "memory");
            __builtin_amdgcn_sched_barrier(0);
            __builtin_amdgcn_s_setprio(1);
#pragma unroll
            for (int s = 0; s < 4; ++s)
#pragma unroll
                for (int kk = 0; kk < 2; ++kk)
#pragma unroll
                    for (int fn = 0; fn < 2; ++fn)
                        acc[h * 4 + s][fn] = __builtin_amdgcn_mfma_f32_16x16x32_bf16(
                            af[s][kk], bfrag[kk][fn], acc[h * 4 + s][fn], 0, 0, 0);
            __builtin_amdgcn_s_setprio(0);
            if (h == 1) {
                if (kt + 2 < nkt) asm volatile("s_waitcnt vmcnt(2)" ::: "memory");
                else              asm volatile("s_waitcnt vmcnt(0)" ::: "memory");
            }
            __builtin_amdgcn_s_barrier();
        }
    }

    // ---- epilogue: bf16 partial to z-selected buffer (fm outer) ----
    ushort_t* pc = (blockIdx.z == 0) ? P0 : P1;
#pragma unroll
    for (int fm = 0; fm < 8; ++fm) {
        const int row_base = m0 + wr * 128 + fm * 16 + quad * 4;
#pragma unroll
        for (int fn = 0; fn < 2; ++fn) {
            const int col = n0 + wc * 32 + fn * 16 + l16;
#pragma unroll
            for (int r = 0; r < 4; ++r)
                pc[(size_t)(row_base + r) * N + col] = f2bf(acc[fm][fn][r]);
        }
    }
}

// ---------------- Flash attention (causal), MFMA, kt-parallel waves ----------
// O and l are linear in kt (no running max) => waves split (row-half wr,
// kt-stripe ws); K/V stream L2->registers; P in wave-private LDS; zero
// barriers in the k-loop; cross-stripe fp32 reduce once per phase.
__global__ __launch_bounds__(256, 2) void attn_flash(const ushort_t* __restrict__ qP,
                                                     const ushort_t* __restrict__ kP,
                                                     const ushort_t* __restrict__ vP,
                                                     ushort_t* __restrict__ o) {
    __shared__ __align__(16) ushort_t P_lds[4][32 * 72]; // wave-private [32 rows][72]
    __shared__ __align__(16) float Ored[2][32][68];      // per wr: partial O from ws=1
    __shared__ float Lred[2][32];                        // per wr: partial l from ws=1
    const int h = blockIdx.x, p = blockIdx.y, b = blockIdx.z; // h fastest (XCD affinity)
    const int bh = b * H_NUM + h;
    const int tid = threadIdx.x;
    const int wave = tid >> 6, lane = tid & 63;
    const int wr = wave >> 1, ws = wave & 1; // row-half, kt-stripe
    const int quad = lane >> 4, l16 = lane & 15;
    ushort_t* Pw = P_lds[wave];
    const ushort_t* kbase = kP + (size_t)bh * 32 * 4096;
    const ushort_t* vbase = vP + (size_t)bh * 32 * 4096;
    bf16x8 onesf;
#pragma unroll
    for (int j = 0; j < 8; ++j) onesf[j] = (__bf16)1.0f;

#pragma unroll 1
    for (int phase = 0; phase < 2; ++phase) {
        const int qt = (phase == 0) ? (31 - p) : p;
        const int nkt = qt + 1;
        const ushort_t* qbase = qP + ((size_t)bh * 32 + qt) * 4096;
        bf16x8 qf[2][2]; // [rowgroup][kk]
#pragma unroll
        for (int rg = 0; rg < 2; ++rg)
#pragma unroll
            for (int kk = 0; kk < 2; ++kk)
                qf[rg][kk] = *(const bf16x8*)&qbase[((kk * 4 + quad) * 64 + wr * 32 + rg * 16 + l16) * 8];
        f32x4 oacc[2][4] = {};
        f32x4 lacc[2] = {};
        __syncthreads(); // WAR: previous phase's epilogue reads of Ored/Lred done
        bf16x8 kf[8], vf[8];
        {
            const ushort_t* kb = kbase + (size_t)ws * 4096;
#pragma unroll
            for (int i = 0; i < 8; ++i)
                kf[i] = *(const bf16x8*)&kb[(((i >> 2) * 4 + quad) * 64 + (i & 3) * 16 + l16) * 8];
        }
#pragma unroll 1
        for (int kt = ws; kt < nkt; kt += 2) {
            f32x4 sacc[2][4] = {};
            __builtin_amdgcn_s_setprio(1);
#pragma unroll
            for (int kk = 0; kk < 2; ++kk)
#pragma unroll
                for (int kg = 0; kg < 4; ++kg)
#pragma unroll
                    for (int rg = 0; rg < 2; ++rg)
                        sacc[rg][kg] = __builtin_amdgcn_mfma_f32_16x16x32_bf16(
                            qf[rg][kk], kf[kk * 4 + kg], sacc[rg][kg], 0, 0, 0);
            __builtin_amdgcn_s_setprio(0);
            {
                const ushort_t* vb = vbase + (size_t)kt * 4096;
#pragma unroll
                for (int i = 0; i < 8; ++i)
                    vf[i] = *(const bf16x8*)&vb[(((i >> 2) * 4 + quad) * 64 + (i & 3) * 16 + l16) * 8];
            }
            if (kt + 2 < nkt) {
                const ushort_t* kb = kbase + (size_t)(kt + 2) * 4096;
#pragma unroll
                for (int i = 0; i < 8; ++i)
                    kf[i] = *(const bf16x8*)&kb[(((i >> 2) * 4 + quad) * 64 + (i & 3) * 16 + l16) * 8];
            }
#pragma unroll
            for (int rg = 0; rg < 2; ++rg)
#pragma unroll
                for (int kg = 0; kg < 4; ++kg) {
                    f32x4 sv = sacc[rg][kg];
                    if (kt == qt) { // wave-uniform branch
                        const int jc = kg * 16 + l16;
#pragma unroll
                        for (int r = 0; r < 4; ++r)
                            if (jc > wr * 32 + rg * 16 + quad * 4 + r) sv[r] = -3.0e38f;
                    }
#pragma unroll
                    for (int r = 0; r < 4; ++r) {
                        const float e = exp2f(sv[r]);
                        Pw[(rg * 16 + quad * 4 + r) * 72 + kg * 16 + l16] =
                            (ushort_t)(__float_as_uint(e) >> 16);
                    }
                }
            __builtin_amdgcn_s_setprio(1);
#pragma unroll
            for (int kk = 0; kk < 2; ++kk)
#pragma unroll
                for (int rg = 0; rg < 2; ++rg) {
                    bf16x8 pf = *(const bf16x8*)&Pw[(rg * 16 + l16) * 72 + kk * 32 + quad * 8];
                    lacc[rg] = __builtin_amdgcn_mfma_f32_16x16x32_bf16(pf, onesf, lacc[rg], 0, 0, 0);
#pragma unroll
                    for (int dg = 0; dg < 4; ++dg)
                        oacc[rg][dg] = __builtin_amdgcn_mfma_f32_16x16x32_bf16(
                            pf, vf[kk * 4 + dg], oacc[rg][dg], 0, 0, 0);
                }
            __builtin_amdgcn_s_setprio(0);
        }
        if (ws == 1) {
#pragma unroll
            for (int rg = 0; rg < 2; ++rg) {
#pragma unroll
                for (int dg = 0; dg < 4; ++dg)
#pragma unroll
                    for (int r = 0; r < 4; ++r)
                        Ored[wr][rg * 16 + quad * 4 + r][dg * 16 + l16] = oacc[rg][dg][r];
                if (l16 == 0) {
#pragma unroll
                    for (int r = 0; r < 4; ++r)
                        Lred[wr][rg * 16 + quad * 4 + r] = lacc[rg][r];
                }
            }
        }
        __syncthreads();
        if (ws == 0) {
#pragma unroll
            for (int rg = 0; rg < 2; ++rg)
#pragma unroll
                for (int r = 0; r < 4; ++r) {
                    const int rr = rg * 16 + quad * 4 + r;
                    const float inv = 1.0f / (lacc[rg][r] + Lred[wr][rr]);
                    const int trow = qt * 64 + wr * 32 + rr;
#pragma unroll
                    for (int dg = 0; dg < 4; ++dg) {
                        const float v = oacc[rg][dg][r] + Ored[wr][rr][dg * 16 + l16];
                        o[(size_t)(b * T_SEQ + trow) * E_DIM + h * HD_DIM + dg * 16 + l16] =
                            f2bf(v * inv);
                    }
                }
        }
    }
}

// ---------------- Host launcher ----------------
extern "C" void kernel_launch(void* const* d_in, const int* in_sizes, int n_in,
                              void* d_out, int out_size, void* d_ws, size_t ws_size,
                              hipStream_t stream) {
    const float* x = (const float*)d_in[0];
    const float* Wq = (const float*)d_in[1];
    const float* Wk = (const float*)d_in[2];
    const float* Wv = (const float*)d_in[3];
    const float* Wproj = (const float*)d_in[4];
    const float* bproj = (const float*)d_in[5];
    const float* W1 = (const float*)d_in[6];
    const float* b1 = (const float*)d_in[7];
    const float* W2 = (const float*)d_in[8];
    const float* b2 = (const float*)d_in[9];
    const float* g1 = (const float*)d_in[10];
    const float* be1 = (const float*)d_in[11];
    const float* g2 = (const float*)d_in[12];
    const float* be2 = (const float*)d_in[13];

    // Workspace layout (80 MB, lifetime-overlapped):
    //  [0,8)    W2T bf16              setup -> FFN2
    //  [8,24)   x1 fp32               reduce_ln -> reduce_out
    //  [24,32)  W1T bf16              setup -> FFN1;  then FFN2 partial fp1 @24
    //  [32,34)  WprojT bf16           setup -> proj
    //  [34,42)  hln/ocat bf16         hln: LN1->QKV; ocat: attn->proj
    //  [42,48)  WqkvT bf16            setup -> QKV
    //  [48,72)  qP/kP/vP bf16 packed  QKV -> attn;  then proj partials pp0@48 pp1@56
    //  [72,80)  h2 bf16               reduce_ln -> FFN1
    //  f1 bf16 32MB @34 [34,66)      FFN1 -> FFN2 (overlays hln/WqkvT/qP/kP/vP-head)
    //  FFN2 partials: fp0 @66 [66,74), fp1 @24 [24,32)  (FFN2 -> reduce_out)
    char* ws = (char*)d_ws;
    const size_t MB = 1024 * 1024;
    ushort_t* W2T    = (ushort_t*)(ws + 0 * MB);
    float*    x1     = (float*)   (ws + 8 * MB);
    ushort_t* W1T    = (ushort_t*)(ws + 24 * MB);
    ushort_t* WprojT = (ushort_t*)(ws + 32 * MB);
    ushort_t* hln    = (ushort_t*)(ws + 34 * MB);
    ushort_t* ocat   = hln;
    ushort_t* WqkvT  = (ushort_t*)(ws + 42 * MB);
    ushort_t* qP     = (ushort_t*)(ws + 48 * MB);
    ushort_t* kP     = (ushort_t*)(ws + 56 * MB);
    ushort_t* vP     = (ushort_t*)(ws + 64 * MB);
    ushort_t* h2     = (ushort_t*)(ws + 72 * MB);
    ushort_t* f1     = (ushort_t*)(ws + 34 * MB);
    ushort_t* pp0    = (ushort_t*)(ws + 48 * MB); // proj partial z=0 (over qP)
    ushort_t* pp1    = (ushort_t*)(ws + 56 * MB); // proj partial z=1 (over kP)
    ushort_t* fp0    = (ushort_t*)(ws + 66 * MB); // FFN2 partial z=0
    ushort_t* fp1    = (ushort_t*)(ws + 24 * MB); // FFN2 partial z=1 (over W1T)
    (void)ws_size; (void)in_sizes; (void)n_in; (void)out_size;

    // All four weight transposes in one launch
    transpose_all_kernel<<<12288, dim3(32, 8, 1), 0, stream>>>(
        Wq, Wk, Wv, Wproj, W1, W2, WqkvT, WprojT, W1T, W2T);

    ln_kernel<<<N_TOK, 256, 0, stream>>>(x, g1, be1, hln);
    // QKV: 256x192 8-phase, grid 16x16 = 256 blocks full fill
    gemm192_qkv<<<dim3(16, 16), 512, 0, stream>>>(hln, WqkvT, qP, kP, vP, E_DIM, E_DIM);
    // h fastest -> id%8 = h%8 -> per-XCD K/V working set 2 MB (L2-resident)
    attn_flash<<<dim3(16, 16, 2), 256, 0, stream>>>(qP, kP, vP, ocat);
    // proj split-K=2: 256x128 thick-phase (8x16x2 = 256 blocks, K-slice 512)
    gemm128n<<<dim3(8, 16, 2), 512, 0, stream>>>(ocat, WprojT, pp0, pp1,
                                                 E_DIM, 512, E_DIM);
    // fused: x1 = x + bproj + pp0 + pp1 ; h2 = LN2(x1)
    reduce_ln_kernel<<<N_TOK, 256, 0, stream>>>(pp0, pp1, x, bproj, g2, be2, x1, h2);
    // FFN1 + bias + relu -> f1 bf16: 256x256 8-phase kernel (256 blocks = 1/CU)
    gemm256_ffn1<<<dim3(16, 16), 512, 0, stream>>>(h2, W1T, b1, f1, FF_DIM, E_DIM, E_DIM);
    // FFN2 split-K=2: 256x128 thick-phase (8x16x2 = 256 blocks, K-slice 2048)
    // (r8: 16 MFMA/phase; r7's 8-MFMA phases regressed 48.6->53.1us)
    gemm128n<<<dim3(8, 16, 2), 512, 0, stream>>>(f1, W2T, fp0, fp1,
                                                 E_DIM, 2048, FF_DIM);
    // d_out = x1 + b2 + fp0 + fp1
    reduce_out_kernel<<<N_TOK, 256, 0, stream>>>(fp0, fp1, x1, b2, (float*)d_out);
}

// Round 9
// 308.318 us; speedup vs baseline: 1.0624x; 1.0196x over previous
//
#include <hip/hip_runtime.h>
#include <hip/hip_bf16.h>
#include <stdint.h>

// Problem constants (B,T,E,H,HD,FF) = (2,2048,1024,16,64,4096).
// I/O dtype: float32. Internal GEMM/attention compute: bf16 MFMA, fp32 accumulate.
#define T_SEQ 2048
#define E_DIM 1024
#define H_NUM 16
#define HD_DIM 64
#define FF_DIM 4096
#define B_NUM 2
#define N_TOK (B_NUM * T_SEQ) // 4096 token rows

typedef unsigned short ushort_t;
typedef __bf16 bf16x8 __attribute__((ext_vector_type(8)));
typedef float f32x4 __attribute__((ext_vector_type(4)));

__device__ __forceinline__ float bf2f(ushort_t u) {
    return __uint_as_float(((unsigned)u) << 16);
}
__device__ __forceinline__ ushort_t f2bf(float f) {
    unsigned u = __float_as_uint(f);
    u += 0x7fffu + ((u >> 16) & 1u);   // round-to-nearest-even
    return (ushort_t)(u >> 16);
}
__device__ __forceinline__ float bflo(unsigned u) { return __uint_as_float(u << 16); }
__device__ __forceinline__ float bfhi(unsigned u) { return __uint_as_float(u & 0xffff0000u); }

// Async global->LDS, 16B per lane. LDS dst is wave-uniform base + lane*16 in
// issue order -> LDS image layout is contiguous in ci order.
__device__ __forceinline__ void async_copy16(const ushort_t* g, ushort_t* l) {
    __builtin_amdgcn_global_load_lds(
        (__attribute__((address_space(1))) uint32_t*)(ushort_t*)g,
        (__attribute__((address_space(3))) uint32_t*)l, 16, 0, 0);
}

// ---------------- LayerNorm: one block per row of 1024; fp32 in, bf16 out ----
__global__ __launch_bounds__(256) void ln_kernel(const float* __restrict__ x,
                                                 const float* __restrict__ g,
                                                 const float* __restrict__ be,
                                                 ushort_t* __restrict__ out) {
    __shared__ float red[8];
    const int row = blockIdx.x, tid = threadIdx.x;
    const float* xr = x + (size_t)row * E_DIM;
    float4 v = ((const float4*)xr)[tid];   // 4 fp32 per thread
    float s = v.x + v.y + v.z + v.w;
    float sq = v.x * v.x + v.y * v.y + v.z * v.z + v.w * v.w;
    for (int off = 32; off; off >>= 1) {
        s += __shfl_xor(s, off);
        sq += __shfl_xor(sq, off);
    }
    const int wid = tid >> 6, lane = tid & 63;
    if (lane == 0) { red[wid] = s; red[4 + wid] = sq; }
    __syncthreads();
    s = red[0] + red[1] + red[2] + red[3];
    sq = red[4] + red[5] + red[6] + red[7];
    const float mean = s * (1.0f / E_DIM);
    const float var = sq * (1.0f / E_DIM) - mean * mean;
    const float rstd = rsqrtf(var + 1e-5f);
    float4 gv = ((const float4*)g)[tid];
    float4 bv = ((const float4*)be)[tid];
    unsigned o0 = f2bf((v.x - mean) * rstd * gv.x + bv.x);
    unsigned o1 = f2bf((v.y - mean) * rstd * gv.y + bv.y);
    unsigned o2 = f2bf((v.z - mean) * rstd * gv.z + bv.z);
    unsigned o3 = f2bf((v.w - mean) * rstd * gv.w + bv.w);
    uint2 w;
    w.x = o0 | (o1 << 16);
    w.y = o2 | (o3 << 16);
    ((uint2*)(out + (size_t)row * E_DIM))[tid] = w;
}

// ---- proj split-K reduce + residual + LN2 fused: one block per token row ----
// v = x + bproj + p0 + p1 ; x1 = v (fp32) ; h2 = LN(v)*g2+be2 (bf16)
__global__ __launch_bounds__(256) void reduce_ln_kernel(const ushort_t* __restrict__ p0,
                                                        const ushort_t* __restrict__ p1,
                                                        const float* __restrict__ x,
                                                        const float* __restrict__ bias,
                                                        const float* __restrict__ g,
                                                        const float* __restrict__ be,
                                                        float* __restrict__ x1,
                                                        ushort_t* __restrict__ h2) {
    __shared__ float red[8];
    const int row = blockIdx.x, tid = threadIdx.x;
    uint2 u0 = ((const uint2*)(p0 + (size_t)row * E_DIM))[tid];
    uint2 u1 = ((const uint2*)(p1 + (size_t)row * E_DIM))[tid];
    float4 xv = ((const float4*)(x + (size_t)row * E_DIM))[tid];
    float4 bv = ((const float4*)bias)[tid];
    float4 v;
    v.x = xv.x + bv.x + bflo(u0.x) + bflo(u1.x);
    v.y = xv.y + bv.y + bfhi(u0.x) + bfhi(u1.x);
    v.z = xv.z + bv.z + bflo(u0.y) + bflo(u1.y);
    v.w = xv.w + bv.w + bfhi(u0.y) + bfhi(u1.y);
    ((float4*)(x1 + (size_t)row * E_DIM))[tid] = v;
    float s = v.x + v.y + v.z + v.w;
    float sq = v.x * v.x + v.y * v.y + v.z * v.z + v.w * v.w;
    for (int off = 32; off; off >>= 1) {
        s += __shfl_xor(s, off);
        sq += __shfl_xor(sq, off);
    }
    const int wid = tid >> 6, lane = tid & 63;
    if (lane == 0) { red[wid] = s; red[4 + wid] = sq; }
    __syncthreads();
    s = red[0] + red[1] + red[2] + red[3];
    sq = red[4] + red[5] + red[6] + red[7];
    const float mean = s * (1.0f / E_DIM);
    const float var = sq * (1.0f / E_DIM) - mean * mean;
    const float rstd = rsqrtf(var + 1e-5f);
    float4 gv = ((const float4*)g)[tid];
    float4 ev = ((const float4*)be)[tid];
    unsigned o0 = f2bf((v.x - mean) * rstd * gv.x + ev.x);
    unsigned o1 = f2bf((v.y - mean) * rstd * gv.y + ev.y);
    unsigned o2 = f2bf((v.z - mean) * rstd * gv.z + ev.z);
    unsigned o3 = f2bf((v.w - mean) * rstd * gv.w + ev.w);
    uint2 w;
    w.x = o0 | (o1 << 16);
    w.y = o2 | (o3 << 16);
    ((uint2*)(h2 + (size_t)row * E_DIM))[tid] = w;
}

// ---- FFN2 split-K reduce + bias + residual: d_out = x1 + b2 + p0 + p1 ------
__global__ __launch_bounds__(256) void reduce_out_kernel(const ushort_t* __restrict__ p0,
                                                         const ushort_t* __restrict__ p1,
                                                         const float* __restrict__ x1,
                                                         const float* __restrict__ bias,
                                                         float* __restrict__ out) {
    const int row = blockIdx.x, tid = threadIdx.x;
    uint2 u0 = ((const uint2*)(p0 + (size_t)row * E_DIM))[tid];
    uint2 u1 = ((const uint2*)(p1 + (size_t)row * E_DIM))[tid];
    float4 xv = ((const float4*)(x1 + (size_t)row * E_DIM))[tid];
    float4 bv = ((const float4*)bias)[tid];
    float4 v;
    v.x = xv.x + bv.x + bflo(u0.x) + bflo(u1.x);
    v.y = xv.y + bv.y + bfhi(u0.x) + bfhi(u1.x);
    v.z = xv.z + bv.z + bflo(u0.y) + bflo(u1.y);
    v.w = xv.w + bv.w + bfhi(u0.y) + bfhi(u1.y);
    ((float4*)(out + (size_t)row * E_DIM))[tid] = v;
}

// -------- Merged convert-transposes (fp32 weights -> bf16 B^T layouts) -------
//   [0,3072)      Wq/Wk/Wv [H][1024][64] -> WqkvT rows (mat*1024+h*64+d) over E
//   [3072,4096)   Wproj 1024x1024 -> WprojT
//   [4096,8192)   W1 1024x4096 -> W1T
//   [8192,12288)  W2 4096x1024 -> W2T
__global__ __launch_bounds__(256) void transpose_all_kernel(const float* __restrict__ Wq,
                                                            const float* __restrict__ Wk,
                                                            const float* __restrict__ Wv,
                                                            const float* __restrict__ Wproj,
                                                            const float* __restrict__ W1,
                                                            const float* __restrict__ W2,
                                                            ushort_t* __restrict__ WqkvT,
                                                            ushort_t* __restrict__ WprojT,
                                                            ushort_t* __restrict__ W1T,
                                                            ushort_t* __restrict__ W2T) {
    __shared__ ushort_t tile[32][33];
    const int id = blockIdx.x;
    const float* in;
    ushort_t* out;
    int R, C, r0, c0;
    if (id < 3072) {
        const int z = id >> 6, rem = id & 63;   // z: 3 mats x 16 heads
        const int m = z >> 4, hh = z & 15;
        in = ((m == 0) ? Wq : ((m == 1) ? Wk : Wv)) + (size_t)hh * E_DIM * HD_DIM; // [1024][64]
        out = WqkvT + (size_t)(m * E_DIM + hh * HD_DIM) * E_DIM;
        R = E_DIM; C = HD_DIM;
        c0 = (rem & 1) * 32; r0 = (rem >> 1) * 32;
    } else if (id < 4096) {
        const int i = id - 3072;
        in = Wproj; out = WprojT; R = E_DIM; C = E_DIM;
        c0 = (i & 31) * 32; r0 = (i >> 5) * 32;
    } else if (id < 8192) {
        const int i = id - 4096;
        in = W1; out = W1T; R = E_DIM; C = FF_DIM;
        c0 = (i & 127) * 32; r0 = (i >> 7) * 32;
    } else {
        const int i = id - 8192;
        in = W2; out = W2T; R = FF_DIM; C = E_DIM;
        c0 = (i & 31) * 32; r0 = (i >> 5) * 32;
    }
    const int tx = threadIdx.x, ty = threadIdx.y;
#pragma unroll
    for (int i = 0; i < 32; i += 8) tile[ty + i][tx] = f2bf(in[(size_t)(r0 + ty + i) * C + (c0 + tx)]);
    __syncthreads();
#pragma unroll
    for (int i = 0; i < 32; i += 8) out[(size_t)(c0 + ty + i) * R + (r0 + tx)] = tile[tx][ty + i];
}

// ---------------- 256x256 THICK-phase GEMM (T2+T4+T5), FFN1 -----------------
// r9: 2 phases/kt, 32 MFMA/phase (was 4 phases/16 MFMA). r8's gemm128n A/B
// proved phase-density is the lever at constant ledger discipline (8->16
// MFMA/phase = -15%); barriers/kt 8->4.
// Grid (N/256, M/256), 512 thr, 8 waves 2Mx4N; per-wave C = 128x64.
// Phase h of kt computes m-subrows 4h..4h+3 x 2kk x 4fn = 32 MFMA.
// Staging: h0 = BOTH A-halves(kt+1) -> buf^1 (4 loads/thr);
//          h1 = BOTH B-halves(kt+2) -> buf  (4 loads/thr).
// Liveness: A(buf^1) last read kt-1 h1 (barrier separates); B(buf) last
// read kt h0 (barrier separates).
// vmcnt ledger (steady state at h1 end): outstanding = B(kt+1)[4, kt-1 h1] +
// A(kt+1)[4, h0] + B(kt+2)[4, h1] = 12 -> vmcnt(4) leaves exactly B(kt+2);
// A(kt+1)+B(kt+1) landed for kt+1 h0. Prologue: A(0)h0h1 + B(0) + B(1) = 12
// loads; vmcnt(4). Tail kt+2>=nkt -> vmcnt(0) (REQUIRED: vmcnt(4) would
// leave A(kt+1) flying when B(kt+2) is not staged).
// LDS XOR swizzle (T2): 16B chunk' = chunk ^ (row&7) on global src + ds_read
// addr (rule #21; r1 measured BANK_CONFLICT 4.19M->0). Epilogue fm-outer
// (r2 verified: no partial-line L2 writeback amplification).
__global__ __launch_bounds__(512, 2) void gemm256_ffn1(const ushort_t* __restrict__ A,
                                                       const ushort_t* __restrict__ BT,
                                                       const float* __restrict__ bias,
                                                       ushort_t* __restrict__ C,
                                                       int N, int K, int lda) {
    __shared__ __align__(16) ushort_t lds_a[2][16384]; // [buf][half:2][128 rows][64 k]
    __shared__ __align__(16) ushort_t lds_b[2][16384];
    const int tid = threadIdx.x;
    // XCD-band swizzle (gridDim.y % 8 == 0; bijective since gy%8==0)
    const int id = blockIdx.y * gridDim.x + blockIdx.x;
    const int band = id & 7, within = id >> 3;
    const int rpb = gridDim.y >> 3;
    const int by = band * rpb + (within % rpb);
    const int bx = within / rpb;
    const int m0 = by * 256, n0 = bx * 256;
    const int wave = tid >> 6, lane = tid & 63;
    const int wr = wave >> 2, wc = wave & 3; // 2M x 4N wave grid
    const int quad = lane >> 4, l16 = lane & 15;
    const int nkt = K >> 6;

    f32x4 acc[8][4] = {};

    auto stageA = [&](int kt, int half) {
        ushort_t* dst = &lds_a[kt & 1][half * 8192];
        const ushort_t* src = A + (size_t)(m0 + half * 128) * lda + kt * 64;
#pragma unroll
        for (int it = 0; it < 2; ++it) {
            const int ci = it * 512 + tid;
            const int r = ci >> 3, c = ci & 7;
            async_copy16(src + (size_t)r * lda + ((c ^ (r & 7)) << 3), dst + ci * 8);
        }
    };
    auto stageB = [&](int kt, int half) {
        ushort_t* dst = &lds_b[kt & 1][half * 8192];
        const ushort_t* src = BT + (size_t)(n0 + half * 128) * lda + kt * 64;
#pragma unroll
        for (int it = 0; it < 2; ++it) {
            const int ci = it * 512 + tid;
            const int r = ci >> 3, c = ci & 7;
            async_copy16(src + (size_t)r * lda + ((c ^ (r & 7)) << 3), dst + ci * 8);
        }
    };

    // Prologue: A(0), B(0), B(1) = 12 loads. A(1) comes at kt=0 h0.
    stageA(0, 0); stageA(0, 1);
    stageB(0, 0); stageB(0, 1);
    stageB(1, 0); stageB(1, 1);
    asm volatile("s_waitcnt vmcnt(4)" ::: "memory"); // A(0)+B(0) landed; B(1) in flight
    __builtin_amdgcn_s_barrier();

    const int swz = l16 & 7; // row&7 for all this lane's fragment rows

#pragma unroll 1
    for (int kt = 0; kt < nkt; ++kt) {
        const int buf = kt & 1;
        const ushort_t* la = &lds_a[buf][wr * 8192];           // wave's A half
        const ushort_t* lb = &lds_b[buf][(wc >> 1) * 8192];    // wave's B half
        const int brow = (wc & 1) * 64;
        bf16x8 bfrag[2][4]; // [kk][fn], held across both phases
#pragma unroll
        for (int h = 0; h < 2; ++h) {
            // ---- ds-reads for this phase: 4 m-subrows x 2 kk ----
            bf16x8 af[4][2];
#pragma unroll
            for (int s = 0; s < 4; ++s) {
                const int r = (h * 4 + s) * 16 + l16;
#pragma unroll
                for (int kk = 0; kk < 2; ++kk)
                    af[s][kk] = *(const bf16x8*)&la[r * 64 + (((kk << 2) + quad) ^ swz) * 8];
            }
            if (h == 0) {
#pragma unroll
                for (int kk = 0; kk < 2; ++kk)
#pragma unroll
                    for (int fn = 0; fn < 4; ++fn) {
                        const int r = brow + fn * 16 + l16;
                        bfrag[kk][fn] = *(const bf16x8*)&lb[r * 64 + (((kk << 2) + quad) ^ swz) * 8];
                    }
            }
            // ---- staging: h0 = both A halves(kt+1); h1 = both B halves(kt+2)
            if (h == 0) {
                if (kt + 1 < nkt) { stageA(kt + 1, 0); stageA(kt + 1, 1); }
            } else {
                if (kt + 2 < nkt) { stageB(kt + 2, 0); stageB(kt + 2, 1); }
            }

            __builtin_amdgcn_s_barrier();
            asm volatile("s_waitcnt lgkmcnt(0)" ::: "memory");
            __builtin_amdgcn_sched_barrier(0);
            __builtin_amdgcn_s_setprio(1);
#pragma unroll
            for (int s = 0; s < 4; ++s)
#pragma unroll
                for (int kk = 0; kk < 2; ++kk)
#pragma unroll
                    for (int fn = 0; fn < 4; ++fn)
                        acc[h * 4 + s][fn] = __builtin_amdgcn_mfma_f32_16x16x32_bf16(
                            af[s][kk], bfrag[kk][fn], acc[h * 4 + s][fn], 0, 0, 0);
            __builtin_amdgcn_s_setprio(0);
            if (h == 1) {
                if (kt + 2 < nkt) asm volatile("s_waitcnt vmcnt(4)" ::: "memory");
                else              asm volatile("s_waitcnt vmcnt(0)" ::: "memory");
            }
            __builtin_amdgcn_s_barrier();
        }
    }

    // ---- epilogue: relu(acc + bias) -> bf16 (fm outer: dense row spans) ----
#pragma unroll
    for (int fm = 0; fm < 8; ++fm) {
        const int row_base = m0 + wr * 128 + fm * 16 + quad * 4;
#pragma unroll
        for (int fn = 0; fn < 4; ++fn) {
            const int col = n0 + wc * 64 + fn * 16 + l16;
            const float bv = bias[col];
#pragma unroll
            for (int r = 0; r < 4; ++r)
                C[(size_t)(row_base + r) * N + col] =
                    f2bf(fmaxf(acc[fm][fn][r] + bv, 0.0f));
        }
    }
}

// ------------- 256x192 THICK-phase GEMM for QKV (full 256-block fill) -------
// r9: 2 phases/kt, 24 MFMA/phase (was 4 phases/12 MFMA -- the thinnest of the
// trio and the worst per-MFMA rate). Barriers/kt 8->4.
// N=3072 -> BN=192: grid 16x16 = 256 blocks = 1/CU full fill. Per-wave C =
// 128x48. LDS = A 64KB + B 48KB = 112KB.
// Phase h computes m-subrows 4h..4h+3 x 2kk x 3fn = 24 MFMA.
// Staging: h0 = both A-halves(kt+1) (4 loads/thr); h1 = B(kt+2) full 192x64
// tile (3 loads/thr).
// vmcnt ledger (h1 end): outstanding = B(kt+1)[3] + A(kt+1)[4] + B(kt+2)[3]
// = 10 -> vmcnt(3) leaves exactly B(kt+2); A(kt+1)+B(kt+1) landed. Prologue:
// A(0)[4]+B(0)[3]+B(1)[3] = 10 loads; vmcnt(3). Tail kt+2>=nkt -> vmcnt(0).
// Scatter epilogue = verified ideal 24.6MB WRITE mapping, fm-outer.
__global__ __launch_bounds__(512, 2) void gemm192_qkv(const ushort_t* __restrict__ A,
                                                      const ushort_t* __restrict__ BT,
                                                      ushort_t* __restrict__ qP,
                                                      ushort_t* __restrict__ kP,
                                                      ushort_t* __restrict__ vP,
                                                      int K, int lda) {
    __shared__ __align__(16) ushort_t lds_a[2][16384]; // [buf][half:2][128 rows][64 k]
    __shared__ __align__(16) ushort_t lds_b[2][12288]; // [buf][192 rows][64 k]
    const int tid = threadIdx.x;
    const int id = blockIdx.y * gridDim.x + blockIdx.x;
    const int band = id & 7, within = id >> 3;
    const int rpb = gridDim.y >> 3; // 2
    const int by = band * rpb + (within % rpb);
    const int bx = within / rpb;
    const int m0 = by * 256, n0 = bx * 192;
    const int wave = tid >> 6, lane = tid & 63;
    const int wr = wave >> 2, wc = wave & 3; // 2M x 4N wave grid, 48 cols/wave
    const int quad = lane >> 4, l16 = lane & 15;
    const int nkt = K >> 6;

    f32x4 acc[8][3] = {};

    auto stageA = [&](int kt, int half) {
        ushort_t* dst = &lds_a[kt & 1][half * 8192];
        const ushort_t* src = A + (size_t)(m0 + half * 128) * lda + kt * 64;
#pragma unroll
        for (int it = 0; it < 2; ++it) {
            const int ci = it * 512 + tid;
            const int r = ci >> 3, c = ci & 7;
            async_copy16(src + (size_t)r * lda + ((c ^ (r & 7)) << 3), dst + ci * 8);
        }
    };
    auto stageB = [&](int kt) { // full 192x64 tile, 3 loads/thread
        ushort_t* dst = lds_b[kt & 1];
        const ushort_t* src = BT + (size_t)n0 * lda + kt * 64;
#pragma unroll
        for (int it = 0; it < 3; ++it) {
            const int ci = it * 512 + tid;
            const int r = ci >> 3, c = ci & 7;
            async_copy16(src + (size_t)r * lda + ((c ^ (r & 7)) << 3), dst + ci * 8);
        }
    };

    stageA(0, 0); stageA(0, 1);
    stageB(0);
    stageB(1);
    asm volatile("s_waitcnt vmcnt(3)" ::: "memory"); // A(0)+B(0) landed; B(1) in flight
    __builtin_amdgcn_s_barrier();

    const int swz = l16 & 7;

#pragma unroll 1
    for (int kt = 0; kt < nkt; ++kt) {
        const int buf = kt & 1;
        const ushort_t* la = &lds_a[buf][wr * 8192]; // wave's 128-row A half
        const ushort_t* lb = lds_b[buf];
        const int brow = wc * 48;
        bf16x8 bfrag[2][3]; // [kk][fn], held across both phases
#pragma unroll
        for (int h = 0; h < 2; ++h) {
            bf16x8 af[4][2];
#pragma unroll
            for (int s = 0; s < 4; ++s) {
                const int r = (h * 4 + s) * 16 + l16;
#pragma unroll
                for (int kk = 0; kk < 2; ++kk)
                    af[s][kk] = *(const bf16x8*)&la[r * 64 + (((kk << 2) + quad) ^ swz) * 8];
            }
            if (h == 0) {
#pragma unroll
                for (int kk = 0; kk < 2; ++kk)
#pragma unroll
                    for (int fn = 0; fn < 3; ++fn) {
                        const int r = brow + fn * 16 + l16;
                        bfrag[kk][fn] = *(const bf16x8*)&lb[r * 64 + (((kk << 2) + quad) ^ swz) * 8];
                    }
            }
            // ---- staging: h0 = both A halves(kt+1); h1 = B(kt+2) ----
            if (h == 0) {
                if (kt + 1 < nkt) { stageA(kt + 1, 0); stageA(kt + 1, 1); }
            } else {
                if (kt + 2 < nkt) stageB(kt + 2);
            }

            __builtin_amdgcn_s_barrier();
            asm volatile("s_waitcnt lgkmcnt(0)" ::: "memory");
            __builtin_amdgcn_sched_barrier(0);
            __builtin_amdgcn_s_setprio(1);
#pragma unroll
            for (int s = 0; s < 4; ++s)
#pragma unroll
                for (int kk = 0; kk < 2; ++kk)
#pragma unroll
                    for (int fn = 0; fn < 3; ++fn)
                        acc[h * 4 + s][fn] = __builtin_amdgcn_mfma_f32_16x16x32_bf16(
                            af[s][kk], bfrag[kk][fn], acc[h * 4 + s][fn], 0, 0, 0);
            __builtin_amdgcn_s_setprio(0);
            if (h == 1) {
                if (kt + 2 < nkt) asm volatile("s_waitcnt vmcnt(3)" ::: "memory");
                else              asm volatile("s_waitcnt vmcnt(0)" ::: "memory");
            }
            __builtin_amdgcn_s_barrier();
        }
    }

    // ---- scatter epilogue (fm outer) ----
#pragma unroll
    for (int fm = 0; fm < 8; ++fm) {
        const int row_base = m0 + wr * 128 + fm * 16 + quad * 4;
#pragma unroll
        for (int fn = 0; fn < 3; ++fn) {
            const int col = n0 + wc * 48 + fn * 16 + l16; // [0,3072)
            const int mat = col >> 10, c = col & 1023, hh = c >> 6, d = c & 63;
#pragma unroll
            for (int r = 0; r < 4; ++r) {
                const int row = row_base + r;
                const int bb = row >> 11, tt = row & 2047;
                const int bh = bb * H_NUM + hh;
                float v = acc[fm][fn][r];
                size_t idx;
                ushort_t* dst;
                if (mat == 0) {        // qP [bh][qt:32][ch:8][row:64][8], pre-scaled
                    idx = ((((size_t)bh * 32 + (tt >> 6)) * 8 + (d >> 3)) * 64 + (tt & 63)) * 8 + (d & 7);
                    dst = qP;
                    v *= 0.0450842048f; // E^-0.5 * log2(e): softmax runs in exp2 domain
                } else if (mat == 1) { // kP [bh][kt:32][ch:8][key:64][8]
                    idx = ((((size_t)bh * 32 + (tt >> 6)) * 8 + (d >> 3)) * 64 + (tt & 63)) * 8 + (d & 7);
                    dst = kP;
                } else {               // vP [bh][kt:32][kh:8][d:64][8]  (V transposed)
                    idx = ((((size_t)bh * 32 + (tt >> 6)) * 8 + ((tt & 63) >> 3)) * 64 + d) * 8 + (tt & 7);
                    dst = vP;
                }
                dst[idx] = f2bf(v);
            }
        }
    }
}

// ------------- 256x128 THICK-phase split-K GEMM (proj + FFN2) ---------------
// r8 (verified: FFN2 53.1 -> 45.3us): 2 phases/kt, 16 MFMA/phase.
// Grid (N/128, M/256, 2): 256 blocks full fill. Per-wave C = 128x32.
// LDS = A 64KB + B 32KB = 96KB -> 1 block/CU.
// Staging: h0 = BOTH A-halves(kt+1) (4 loads/thr); h1 = B(kt+2) (2 loads/thr).
// vmcnt ledger (h1 end): B(kt+1)[2]+A(kt+1)[4]+B(kt+2)[2] = 8 -> vmcnt(2).
// Prologue: 8 loads; vmcnt(2). Tail kt+2>=nkt -> vmcnt(0).
__global__ __launch_bounds__(512, 2) void gemm128n(const ushort_t* __restrict__ A,
                                                   const ushort_t* __restrict__ BT,
                                                   ushort_t* __restrict__ P0,
                                                   ushort_t* __restrict__ P1,
                                                   int N, int K, int lda) {
    __shared__ __align__(16) ushort_t lds_a[2][16384]; // [buf][half:2][128 rows][64 k]
    __shared__ __align__(16) ushort_t lds_b[2][8192];  // [buf][128 rows][64 k]
    const int tid = threadIdx.x;
    // XCD-band swizzle (gridDim.y = 16, %8 == 0, bijective; z not in swizzle)
    const int id = blockIdx.y * gridDim.x + blockIdx.x;
    const int band = id & 7, within = id >> 3;
    const int rpb = gridDim.y >> 3; // 2
    const int by = band * rpb + (within % rpb);
    const int bx = within / rpb;
    const int m0 = by * 256, n0 = bx * 128;
    const int koff = blockIdx.z * K;
    const int wave = tid >> 6, lane = tid & 63;
    const int wr = wave >> 2, wc = wave & 3; // 2M x 4N wave grid, 32 cols/wave
    const int quad = lane >> 4, l16 = lane & 15;
    const int nkt = K >> 6;

    f32x4 acc[8][2] = {};

    auto stageA = [&](int kt, int half) {
        ushort_t* dst = &lds_a[kt & 1][half * 8192];
        const ushort_t* src = A + (size_t)(m0 + half * 128) * lda + koff + kt * 64;
#pragma unroll
        for (int it = 0; it < 2; ++it) {
            const int ci = it * 512 + tid;
            const int r = ci >> 3, c = ci & 7;
            async_copy16(src + (size_t)r * lda + ((c ^ (r & 7)) << 3), dst + ci * 8);
        }
    };
    auto stageB = [&](int kt) { // full 128x64 tile, 2 loads/thread
        ushort_t* dst = lds_b[kt & 1];
        const ushort_t* src = BT + (size_t)n0 * lda + koff + kt * 64;
#pragma unroll
        for (int it = 0; it < 2; ++it) {
            const int ci = it * 512 + tid;
            const int r = ci >> 3, c = ci & 7;
            async_copy16(src + (size_t)r * lda + ((c ^ (r & 7)) << 3), dst + ci * 8);
        }
    };

    stageA(0, 0); stageA(0, 1);
    stageB(0);
    stageB(1);
    asm volatile("s_waitcnt vmcnt(2)" ::: "memory"); // A(0)+B(0) landed; B(1) in flight
    __builtin_amdgcn_s_barrier();

    const int swz = l16 & 7;

#pragma unroll 1
    for (int kt = 0; kt < nkt; ++kt) {
        const int buf = kt & 1;
        const ushort_t* la = &lds_a[buf][wr * 8192]; // wave's 128-row A half
        const ushort_t* lb = lds_b[buf];
        const int brow = wc * 32;
        bf16x8 bfrag[2][2]; // [kk][fn], held across both phases
#pragma unroll
        for (int h = 0; h < 2; ++h) {
            // ---- ds-reads for this phase: 4 m-subrows x 2 kk ----
            bf16x8 af[4][2];
#pragma unroll
            for (int s = 0; s < 4; ++s) {
                const int r = (h * 4 + s) * 16 + l16;
#pragma unroll
                for (int kk = 0; kk < 2; ++kk)
                    af[s][kk] = *(const bf16x8*)&la[r * 64 + (((kk << 2) + quad) ^ swz) * 8];
            }
            if (h == 0) {
#pragma unroll
                for (int kk = 0; kk < 2; ++kk)
#pragma unroll
                    for (int fn = 0; fn < 2; ++fn) {
                        const int r = brow + fn * 16 + l16;
                        bfrag[kk][fn] = *(const bf16x8*)&lb[r * 64 + (((kk << 2) + quad) ^ swz) * 8];
                    }
            }
            // ---- staging: h0 = both A halves(kt+1); h1 = B(kt+2) ----
            if (h == 0) {
                if (kt + 1 < nkt) { stageA(kt + 1, 0); stageA(kt + 1, 1); }
            } else {
                if (kt + 2 < nkt) stageB(kt + 2);
            }

            __builtin_amdgcn_s_barrier();
            asm volatile("s_waitcnt lgkmcnt(0)" ::: "memory");
            __builtin_amdgcn_sched_barrier(0);
            __builtin_amdgcn_s_setprio(1);
#pragma unroll
            for (int s = 0; s < 4; ++s)
#pragma unroll
                for (int kk = 0; kk < 2; ++kk)
#pragma unroll
                    for (int fn = 0; fn < 2; ++fn)
                        acc[h * 4 + s][fn] = __builtin_amdgcn_mfma_f32_16x16x32_bf16(
                            af[s][kk], bfrag[kk][fn], acc[h * 4 + s][fn], 0, 0, 0);
            __builtin_amdgcn_s_setprio(0);
            if (h == 1) {
                if (kt + 2 < nkt) asm volatile("s_waitcnt vmcnt(2)" ::: "memory");
                else              asm volatile("s_waitcnt vmcnt(0)" ::: "memory");
            }
            __builtin_amdgcn_s_barrier();
        }
    }

    // ---- epilogue: bf16 partial to z-selected buffer (fm outer) ----
    ushort_t* pc = (blockIdx.z == 0) ? P0 : P1;
#pragma unroll
    for (int fm = 0; fm < 8; ++fm) {
        const int row_base = m0 + wr * 128 + fm * 16 + quad * 4;
#pragma unroll
        for (int fn = 0; fn < 2; ++fn) {
            const int col = n0 + wc * 32 + fn * 16 + l16;
#pragma unroll
            for (int r = 0; r < 4; ++r)
                pc[(size_t)(row_base + r) * N + col] = f2bf(acc[fm][fn][r]);
        }
    }
}

// ---------------- Flash attention (causal), MFMA, kt-parallel waves ----------
// O and l are linear in kt (no running max) => waves split (row-half wr,
// kt-stripe ws); K/V stream L2->registers; P in wave-private LDS; zero
// barriers in the k-loop; cross-stripe fp32 reduce once per phase.
__global__ __launch_bounds__(256, 2) void attn_flash(const ushort_t* __restrict__ qP,
                                                     const ushort_t* __restrict__ kP,
                                                     const ushort_t* __restrict__ vP,
                                                     ushort_t* __restrict__ o) {
    __shared__ __align__(16) ushort_t P_lds[4][32 * 72]; // wave-private [32 rows][72]
    __shared__ __align__(16) float Ored[2][32][68];      // per wr: partial O from ws=1
    __shared__ float Lred[2][32];                        // per wr: partial l from ws=1
    const int h = blockIdx.x, p = blockIdx.y, b = blockIdx.z; // h fastest (XCD affinity)
    const int bh = b * H_NUM + h;
    const int tid = threadIdx.x;
    const int wave = tid >> 6, lane = tid & 63;
    const int wr = wave >> 1, ws = wave & 1; // row-half, kt-stripe
    const int quad = lane >> 4, l16 = lane & 15;
    ushort_t* Pw = P_lds[wave];
    const ushort_t* kbase = kP + (size_t)bh * 32 * 4096;
    const ushort_t* vbase = vP + (size_t)bh * 32 * 4096;
    bf16x8 onesf;
#pragma unroll
    for (int j = 0; j < 8; ++j) onesf[j] = (__bf16)1.0f;

#pragma unroll 1
    for (int phase = 0; phase < 2; ++phase) {
        const int qt = (phase == 0) ? (31 - p) : p;
        const int nkt = qt + 1;
        const ushort_t* qbase = qP + ((size_t)bh * 32 + qt) * 4096;
        bf16x8 qf[2][2]; // [rowgroup][kk]
#pragma unroll
        for (int rg = 0; rg < 2; ++rg)
#pragma unroll
            for (int kk = 0; kk < 2; ++kk)
                qf[rg][kk] = *(const bf16x8*)&qbase[((kk * 4 + quad) * 64 + wr * 32 + rg * 16 + l16) * 8];
        f32x4 oacc[2][4] = {};
        f32x4 lacc[2] = {};
        __syncthreads(); // WAR: previous phase's epilogue reads of Ored/Lred done
        bf16x8 kf[8], vf[8];
        {
            const ushort_t* kb = kbase + (size_t)ws * 4096;
#pragma unroll
            for (int i = 0; i < 8; ++i)
                kf[i] = *(const bf16x8*)&kb[(((i >> 2) * 4 + quad) * 64 + (i & 3) * 16 + l16) * 8];
        }
#pragma unroll 1
        for (int kt = ws; kt < nkt; kt += 2) {
            f32x4 sacc[2][4] = {};
            __builtin_amdgcn_s_setprio(1);
#pragma unroll
            for (int kk = 0; kk < 2; ++kk)
#pragma unroll
                for (int kg = 0; kg < 4; ++kg)
#pragma unroll
                    for (int rg = 0; rg < 2; ++rg)
                        sacc[rg][kg] = __builtin_amdgcn_mfma_f32_16x16x32_bf16(
                            qf[rg][kk], kf[kk * 4 + kg], sacc[rg][kg], 0, 0, 0);
            __builtin_amdgcn_s_setprio(0);
            {
                const ushort_t* vb = vbase + (size_t)kt * 4096;
#pragma unroll
                for (int i = 0; i < 8; ++i)
                    vf[i] = *(const bf16x8*)&vb[(((i >> 2) * 4 + quad) * 64 + (i & 3) * 16 + l16) * 8];
            }
            if (kt + 2 < nkt) {
                const ushort_t* kb = kbase + (size_t)(kt + 2) * 4096;
#pragma unroll
                for (int i = 0; i < 8; ++i)
                    kf[i] = *(const bf16x8*)&kb[(((i >> 2) * 4 + quad) * 64 + (i & 3) * 16 + l16) * 8];
            }
#pragma unroll
            for (int rg = 0; rg < 2; ++rg)
#pragma unroll
                for (int kg = 0; kg < 4; ++kg) {
                    f32x4 sv = sacc[rg][kg];
                    if (kt == qt) { // wave-uniform branch
                        const int jc = kg * 16 + l16;
#pragma unroll
                        for (int r = 0; r < 4; ++r)
                            if (jc > wr * 32 + rg * 16 + quad * 4 + r) sv[r] = -3.0e38f;
                    }
#pragma unroll
                    for (int r = 0; r < 4; ++r) {
                        const float e = exp2f(sv[r]);
                        Pw[(rg * 16 + quad * 4 + r) * 72 + kg * 16 + l16] =
                            (ushort_t)(__float_as_uint(e) >> 16);
                    }
                }
            __builtin_amdgcn_s_setprio(1);
#pragma unroll
            for (int kk = 0; kk < 2; ++kk)
#pragma unroll
                for (int rg = 0; rg < 2; ++rg) {
                    bf16x8 pf = *(const bf16x8*)&Pw[(rg * 16 + l16) * 72 + kk * 32 + quad * 8];
                    lacc[rg] = __builtin_amdgcn_mfma_f32_16x16x32_bf16(pf, onesf, lacc[rg], 0, 0, 0);
#pragma unroll
                    for (int dg = 0; dg < 4; ++dg)
                        oacc[rg][dg] = __builtin_amdgcn_mfma_f32_16x16x32_bf16(
                            pf, vf[kk * 4 + dg], oacc[rg][dg], 0, 0, 0);
                }
            __builtin_amdgcn_s_setprio(0);
        }
        if (ws == 1) {
#pragma unroll
            for (int rg = 0; rg < 2; ++rg) {
#pragma unroll
                for (int dg = 0; dg < 4; ++dg)
#pragma unroll
                    for (int r = 0; r < 4; ++r)
                        Ored[wr][rg * 16 + quad * 4 + r][dg * 16 + l16] = oacc[rg][dg][r];
                if (l16 == 0) {
#pragma unroll
                    for (int r = 0; r < 4; ++r)
                        Lred[wr][rg * 16 + quad * 4 + r] = lacc[rg][r];
                }
            }
        }
        __syncthreads();
        if (ws == 0) {
#pragma unroll
            for (int rg = 0; rg < 2; ++rg)
#pragma unroll
                for (int r = 0; r < 4; ++r) {
                    const int rr = rg * 16 + quad * 4 + r;
                    const float inv = 1.0f / (lacc[rg][r] + Lred[wr][rr]);
                    const int trow = qt * 64 + wr * 32 + rr;
#pragma unroll
                    for (int dg = 0; dg < 4; ++dg) {
                        const float v = oacc[rg][dg][r] + Ored[wr][rr][dg * 16 + l16];
                        o[(size_t)(b * T_SEQ + trow) * E_DIM + h * HD_DIM + dg * 16 + l16] =
                            f2bf(v * inv);
                    }
                }
        }
    }
}

// ---------------- Host launcher ----------------
extern "C" void kernel_launch(void* const* d_in, const int* in_sizes, int n_in,
                              void* d_out, int out_size, void* d_ws, size_t ws_size,
                              hipStream_t stream) {
    const float* x = (const float*)d_in[0];
    const float* Wq = (const float*)d_in[1];
    const float* Wk = (const float*)d_in[2];
    const float* Wv = (const float*)d_in[3];
    const float* Wproj = (const float*)d_in[4];
    const float* bproj = (const float*)d_in[5];
    const float* W1 = (const float*)d_in[6];
    const float* b1 = (const float*)d_in[7];
    const float* W2 = (const float*)d_in[8];
    const float* b2 = (const float*)d_in[9];
    const float* g1 = (const float*)d_in[10];
    const float* be1 = (const float*)d_in[11];
    const float* g2 = (const float*)d_in[12];
    const float* be2 = (const float*)d_in[13];

    // Workspace layout (80 MB, lifetime-overlapped):
    //  [0,8)    W2T bf16              setup -> FFN2
    //  [8,24)   x1 fp32               reduce_ln -> reduce_out
    //  [24,32)  W1T bf16              setup -> FFN1;  then FFN2 partial fp1 @24
    //  [32,34)  WprojT bf16           setup -> proj
    //  [34,42)  hln/ocat bf16         hln: LN1->QKV; ocat: attn->proj
    //  [42,48)  WqkvT bf16            setup -> QKV
    //  [48,72)  qP/kP/vP bf16 packed  QKV -> attn;  then proj partials pp0@48 pp1@56
    //  [72,80)  h2 bf16               reduce_ln -> FFN1
    //  f1 bf16 32MB @34 [34,66)      FFN1 -> FFN2 (overlays hln/WqkvT/qP/kP/vP-head)
    //  FFN2 partials: fp0 @66 [66,74), fp1 @24 [24,32)  (FFN2 -> reduce_out)
    char* ws = (char*)d_ws;
    const size_t MB = 1024 * 1024;
    ushort_t* W2T    = (ushort_t*)(ws + 0 * MB);
    float*    x1     = (float*)   (ws + 8 * MB);
    ushort_t* W1T    = (ushort_t*)(ws + 24 * MB);
    ushort_t* WprojT = (ushort_t*)(ws + 32 * MB);
    ushort_t* hln    = (ushort_t*)(ws + 34 * MB);
    ushort_t* ocat   = hln;
    ushort_t* WqkvT  = (ushort_t*)(ws + 42 * MB);
    ushort_t* qP     = (ushort_t*)(ws + 48 * MB);
    ushort_t* kP     = (ushort_t*)(ws + 56 * MB);
    ushort_t* vP     = (ushort_t*)(ws + 64 * MB);
    ushort_t* h2     = (ushort_t*)(ws + 72 * MB);
    ushort_t* f1     = (ushort_t*)(ws + 34 * MB);
    ushort_t* pp0    = (ushort_t*)(ws + 48 * MB); // proj partial z=0 (over qP)
    ushort_t* pp1    = (ushort_t*)(ws + 56 * MB); // proj partial z=1 (over kP)
    ushort_t* fp0    = (ushort_t*)(ws + 66 * MB); // FFN2 partial z=0
    ushort_t* fp1    = (ushort_t*)(ws + 24 * MB); // FFN2 partial z=1 (over W1T)
    (void)ws_size; (void)in_sizes; (void)n_in; (void)out_size;

    // All four weight transposes in one launch
    transpose_all_kernel<<<12288, dim3(32, 8, 1), 0, stream>>>(
        Wq, Wk, Wv, Wproj, W1, W2, WqkvT, WprojT, W1T, W2T);

    ln_kernel<<<N_TOK, 256, 0, stream>>>(x, g1, be1, hln);
    // QKV: 256x192 thick-phase (r9: 24 MFMA/phase), 256 blocks full fill
    gemm192_qkv<<<dim3(16, 16), 512, 0, stream>>>(hln, WqkvT, qP, kP, vP, E_DIM, E_DIM);
    // h fastest -> id%8 = h%8 -> per-XCD K/V working set 2 MB (L2-resident)
    attn_flash<<<dim3(16, 16, 2), 256, 0, stream>>>(qP, kP, vP, ocat);
    // proj split-K=2: 256x128 thick-phase (8x16x2 = 256 blocks, K-slice 512)
    gemm128n<<<dim3(8, 16, 2), 512, 0, stream>>>(ocat, WprojT, pp0, pp1,
                                                 E_DIM, 512, E_DIM);
    // fused: x1 = x + bproj + pp0 + pp1 ; h2 = LN2(x1)
    reduce_ln_kernel<<<N_TOK, 256, 0, stream>>>(pp0, pp1, x, bproj, g2, be2, x1, h2);
    // FFN1 + bias + relu -> f1: 256x256 thick-phase (r9: 32 MFMA/phase)
    gemm256_ffn1<<<dim3(16, 16), 512, 0, stream>>>(h2, W1T, b1, f1, FF_DIM, E_DIM, E_DIM);
    // FFN2 split-K=2: 256x128 thick-phase (r8-verified 16 MFMA/phase)
    gemm128n<<<dim3(8, 16, 2), 512, 0, stream>>>(f1, W2T, fp0, fp1,
                                                 E_DIM, 2048, FF_DIM);
    // d_out = x1 + b2 + fp0 + fp1
    reduce_out_kernel<<<N_TOK, 256, 0, stream>>>(fp0, fp1, x1, b2, (float*)d_out);
}